// Round 4
// baseline (449.696 us; speedup 1.0000x reference)
//
#include <hip/hip_runtime.h>

#define B_  8
#define C_  256
#define C2_ 128
#define N_  4096
#define LOG2E 1.44269504088896f

typedef _Float16 f16;
typedef _Float16 f16x8 __attribute__((ext_vector_type(8)));
typedef float f32x4  __attribute__((ext_vector_type(4)));

static __device__ __forceinline__ unsigned pk2(float a, float b) {
  return __builtin_bit_cast(unsigned, __builtin_amdgcn_cvt_pkrtz(a, b));  // v_cvt_pkrtz_f16_f32
}

// ---------------------------------------------------------------------------
// prep: cast W1/W2 to f16 once (32768 elements each)
// ---------------------------------------------------------------------------
__global__ __launch_bounds__(256)
void prep_kernel(const float* __restrict__ W1, const float* __restrict__ W2,
                 f16* __restrict__ w1h, f16* __restrict__ w2h)
{
  int i = blockIdx.x * 256 + threadIdx.x;   // grid 128 -> 32768
  w1h[i] = (f16)W1[i];
  w2h[i] = (f16)W2[i];
}

// ---------------------------------------------------------------------------
// conv1: Y[b,n,c2] = sum_c x[b,c,n]*W1[c2,c] + b1; dual layout Y + Yt.
// (unchanged from verified baseline)
// ---------------------------------------------------------------------------
__global__ __launch_bounds__(256, 3)
void conv1_kernel(const float* __restrict__ x,
                  const f16* __restrict__ w1h,
                  const float* __restrict__ b1,
                  f16* __restrict__ Y, f16* __restrict__ Yt)
{
  __shared__ __align__(16) char smem[49152];
  float* Xr = (float*)smem;            // [256 c][32 n] f32, float4-block XOR (32 KB)
  f16*   Ah = (f16*)(smem + 32768);    // [32 n][256 k] f16 XOR-8 (16 KB)
  f16*   T  = (f16*)smem;              // [128 c2][40 n] epilogue alias

  const int t = threadIdx.x;
  const int w = t >> 6, lane = t & 63, quad = lane >> 4, l16 = lane & 15;
  const int b = blockIdx.x, nt0 = blockIdx.y;

  // stage all 256c x 32n fp32 (8 outstanding float4 loads)
#pragma unroll
  for (int pass = 0; pass < 8; pass++) {
    int c  = (t >> 3) + pass * 32;            // 0..255
    int n4 = t & 7;
    float4 v = *(const float4*)(x + ((long)(b * C_ + c)) * N_ + nt0 * 32 + n4 * 4);
    *(float4*)(&Xr[c * 32 + (n4 ^ (c & 7)) * 4]) = v;
  }
  __syncthreads();
  // transpose+cvt into Ah [n][k] XOR-8
#pragma unroll
  for (int pass = 0; pass < 4; pass++) {
    int n  = t & 31;
    int kb = (t >> 5) + pass * 8;             // 0..31
    f16x8 vh;
#pragma unroll
    for (int jj = 0; jj < 8; jj++) {
      int cc = kb * 8 + jj;
      vh[jj] = (f16)Xr[cc * 32 + ((n >> 2) ^ (cc & 7)) * 4 + (n & 3)];
    }
    *(f16x8*)(&Ah[n * 256 + (kb ^ (n & 7)) * 8]) = vh;
  }
  __syncthreads();

  // B-frags from global (L2-hot, shared by all WGs)
  f16x8 bh[2][8];
#pragma unroll
  for (int nt = 0; nt < 2; nt++) {
    int c2 = w * 32 + nt * 16 + l16;
#pragma unroll
    for (int ks = 0; ks < 8; ks++)
      bh[nt][ks] = *(const f16x8*)(w1h + c2 * C_ + ks * 32 + quad * 8);
  }

  f32x4 acc[2][2];
#pragma unroll
  for (int i = 0; i < 2; i++)
#pragma unroll
    for (int j = 0; j < 2; j++) acc[i][j] = (f32x4){0.f, 0.f, 0.f, 0.f};

#pragma unroll
  for (int ks = 0; ks < 8; ks++)
#pragma unroll
    for (int mt = 0; mt < 2; mt++) {
      f16x8 ah = *(const f16x8*)(&Ah[(mt * 16 + l16) * 256 + (((ks * 4 + quad) ^ (l16 & 7))) * 8]);
#pragma unroll
      for (int nt = 0; nt < 2; nt++)
        acc[mt][nt] = __builtin_amdgcn_mfma_f32_16x16x32_f16(ah, bh[nt][ks], acc[mt][nt], 0, 0, 0);
    }
  __syncthreads();   // Xr dead -> T alias safe

  // epilogue -> T[c2][n]
#pragma unroll
  for (int nt = 0; nt < 2; nt++) {
    int c2 = w * 32 + nt * 16 + l16;
    float bv = b1[c2];
#pragma unroll
    for (int mt = 0; mt < 2; mt++)
#pragma unroll
      for (int rg = 0; rg < 4; rg++) {
        int n = mt * 16 + quad * 4 + rg;
        T[c2 * 40 + n] = (f16)(acc[mt][nt][rg] + bv);
      }
  }
  __syncthreads();
  // Yt[c2][n]: vec8 along n
#pragma unroll
  for (int pass = 0; pass < 2; pass++) {
    int r  = (t >> 2) + pass * 64;            // c2 0..127
    int c8 = (t & 3) * 8;                     // n
    f16x8 v = *(const f16x8*)(&T[r * 40 + c8]);
    *(f16x8*)(Yt + ((long)(b * C2_ + r)) * N_ + nt0 * 32 + c8) = v;
  }
  // Y[n][c2]: gather
#pragma unroll
  for (int pass = 0; pass < 2; pass++) {
    int row = t & 31;
    int cg  = (t >> 5) + pass * 8;            // c2-block 0..15
    f16x8 v;
#pragma unroll
    for (int jj = 0; jj < 8; jj++) v[jj] = T[(cg * 8 + jj) * 40 + row];
    *(f16x8*)(Y + ((long)(b * N_ + nt0 * 32 + row)) * C2_ + cg * 8) = v;
  }
}

// ---------------------------------------------------------------------------
// attn v4: = v3 (swapped QK^T, register P via permlane32_swap + ds_swizzle
// exchange, baseline conflict-free 16x16x32 PV) generalized to NS splits.
// Split s covers key tiles [s*64/NS, (s+1)*64/NS); grid (8, 32, NS).
// NS=4 -> 1024 blocks = 4 WG/CU (occupancy was grid-limited at 2 WG/CU).
// Chip-wide staging/MFMA/exp work unchanged; only epilogue O-writes scale.
// LDS 32.5 KB -> 4/CU fits; launch_bounds(256,4) caps VGPR at 128.
// ---------------------------------------------------------------------------
__global__ __launch_bounds__(256, 4)
void attn_kernel(const f16* __restrict__ Y, const f16* __restrict__ Yt,
                 f16* __restrict__ Op, float* __restrict__ ls)
{
  __shared__ f16 Ks[64 * 128];   // [key][d]  16B-block pos = (d>>3) ^ (key&15)
  __shared__ f16 Vs[128 * 64];   // [d][k]    pos = (k>>3) ^ (d&7)
  __shared__ float nsqf[128];

  const int t = threadIdx.x;
  const int w = t >> 6, lane = t & 63, quad = lane >> 4, l16 = lane & 15;
  const int b = blockIdx.x, qt = blockIdx.y, s = blockIdx.z;
  const int ns = gridDim.z;
  const f16* Yb  = Y  + (long)b * N_ * C2_;
  const f16* Ytb = Yt + (long)b * C2_ * N_;
  const int g0 = (s * 64) / ns;        // first 64-key tile of this split
  const int g1 = ((s + 1) * 64) / ns;  // one past last

  // Q frags (A/B-frag layout identical for 16x16x32): row q=l16, d-chunk quad*8
  f16x8 qf[2][4];
#pragma unroll
  for (int mt = 0; mt < 2; mt++)
#pragma unroll
    for (int ks = 0; ks < 4; ks++)
      qf[mt][ks] = *(const f16x8*)(Yb + (long)(qt * 128 + w * 32 + mt * 16 + l16) * C2_ + ks * 32 + quad * 8);

  // per-row |y_q|^2 (exact same f16 values the MFMA sees)
  {
    int r = t >> 1, half = t & 1;
    float ss = 0.f;
#pragma unroll
    for (int j = 0; j < 8; j++) {
      f16x8 v = *(const f16x8*)(Yb + (long)(qt * 128 + r) * C2_ + half * 64 + j * 8);
#pragma unroll
      for (int e = 0; e < 8; e++) { float f = (float)v[e]; ss = fmaf(f, f, ss); }
    }
    ss += __shfl_xor(ss, 1);
    if (!half) nsqf[r] = ss;
  }

  // prologue: stage first tile of this split
  {
    const int kb0 = g0 * 64;
#pragma unroll
    for (int pass = 0; pass < 4; pass++) {
      int r = (t >> 4) + pass * 16;
      f16x8 kv = *(const f16x8*)(Yb + (long)(kb0 + r) * C2_ + (t & 15) * 8);
      *(f16x8*)(&Ks[r * 128 + (((t & 15)) ^ (r & 15)) * 8]) = kv;
    }
#pragma unroll
    for (int pass = 0; pass < 4; pass++) {
      int d = (t >> 3) + pass * 32;
      f16x8 vv = *(const f16x8*)(Ytb + (long)d * N_ + kb0 + (t & 7) * 8);
      *(f16x8*)(&Vs[d * 64 + (((t & 7)) ^ (d & 7)) * 8]) = vv;
    }
  }
  __syncthreads();

  // fixed per-row max (log2 units), per-lane by q=l16
  float nm[2];
  nm[0] = nsqf[w * 32 + l16] * LOG2E;
  nm[1] = nsqf[w * 32 + 16 + l16] * LOG2E;

  f16x8 ones8;
#pragma unroll
  for (int j = 0; j < 8; j++) ones8[j] = (f16)1.0f;

  f32x4 Oa[2][8];                 // C-layout: row q = quad*4+rg, col d = l16
#pragma unroll
  for (int i = 0; i < 2; i++)
#pragma unroll
    for (int j = 0; j < 8; j++) Oa[i][j] = (f32x4){0.f, 0.f, 0.f, 0.f};
  f32x4 lac[2] = {(f32x4){0.f,0.f,0.f,0.f}, (f32x4){0.f,0.f,0.f,0.f}};

#pragma unroll 1
  for (int g = g0; g < g1; g++) {
    // prefetch next tile into registers
    f16x8 stK[4], stV[4];
    if (g + 1 < g1) {
      int nb = (g + 1) * 64;
#pragma unroll
      for (int pass = 0; pass < 4; pass++)
        stK[pass] = *(const f16x8*)(Yb + (long)(nb + (t >> 4) + pass * 16) * C2_ + (t & 15) * 8);
#pragma unroll
      for (int pass = 0; pass < 4; pass++)
        stV[pass] = *(const f16x8*)(Ytb + (long)((t >> 3) + pass * 32) * N_ + nb + (t & 7) * 8);
    }

    // S^T = K Q^T : row = key(quad*4+rg within nt), col = q(l16)
    f32x4 S[4][2];
#pragma unroll
    for (int i = 0; i < 4; i++)
#pragma unroll
      for (int j = 0; j < 2; j++) S[i][j] = (f32x4){0.f, 0.f, 0.f, 0.f};
#pragma unroll
    for (int ks = 0; ks < 4; ks++) {
      f16x8 bfr[4];
#pragma unroll
      for (int nt = 0; nt < 4; nt++)
        bfr[nt] = *(const f16x8*)(&Ks[(nt * 16 + l16) * 128 + (((ks * 4 + quad) ^ l16)) * 8]);
#pragma unroll
      for (int nt = 0; nt < 4; nt++)
#pragma unroll
        for (int mt = 0; mt < 2; mt++)
          S[nt][mt] = __builtin_amdgcn_mfma_f32_16x16x32_f16(bfr[nt], qf[mt][ks], S[nt][mt], 0, 0, 0);
    }

    // fixed-max exp -> packed f16 pairs: Xp[mt][nt][d] = keys quad*4+{2d,2d+1}
    unsigned Xp[2][4][2];
#pragma unroll
    for (int mt = 0; mt < 2; mt++)
#pragma unroll
      for (int nt = 0; nt < 4; nt++) {
        float p0 = exp2f(fminf(fmaf(S[nt][mt][0], LOG2E, -nm[mt]), 11.0f));
        float p1 = exp2f(fminf(fmaf(S[nt][mt][1], LOG2E, -nm[mt]), 11.0f));
        float p2 = exp2f(fminf(fmaf(S[nt][mt][2], LOG2E, -nm[mt]), 11.0f));
        float p3 = exp2f(fminf(fmaf(S[nt][mt][3], LOG2E, -nm[mt]), 11.0f));
        Xp[mt][nt][0] = pk2(p0, p1);
        Xp[mt][nt][1] = pk2(p2, p3);
      }

    // register exchange -> PV A-frags pa[ks2][mt] (P[q=l16][k=quad*8..+7])
    f16x8 pa[2][2];
    {
      const bool par = (quad & 1) != 0;
#pragma unroll
      for (int mt = 0; mt < 2; mt++) {
#pragma unroll
        for (int pr = 0; pr < 2; pr++)
#pragma unroll
          for (int d = 0; d < 2; d++) {
            auto r = __builtin_amdgcn_permlane32_swap(Xp[mt][2 * pr][d], Xp[mt][2 * pr + 1][d], false, false);
            Xp[mt][2 * pr][d]     = r[0];   // src quads 0,1 (nt pr*2 lo half, pr*2+1 hi half)
            Xp[mt][2 * pr + 1][d] = r[1];   // src quads 2,3
          }
#pragma unroll
        for (int ks2 = 0; ks2 < 2; ks2++) {
          unsigned lo0 = Xp[mt][2 * ks2][0],     lo1 = Xp[mt][2 * ks2][1];
          unsigned hi0 = Xp[mt][2 * ks2 + 1][0], hi1 = Xp[mt][2 * ks2 + 1][1];
          unsigned lo0x = (unsigned)__builtin_amdgcn_ds_swizzle((int)lo0, 0x401F);  // xor 16
          unsigned lo1x = (unsigned)__builtin_amdgcn_ds_swizzle((int)lo1, 0x401F);
          unsigned hi0x = (unsigned)__builtin_amdgcn_ds_swizzle((int)hi0, 0x401F);
          unsigned hi1x = (unsigned)__builtin_amdgcn_ds_swizzle((int)hi1, 0x401F);
          union { unsigned u[4]; f16x8 v; } P;
          P.u[0] = par ? hi0x : lo0;   // k quad*8 + {0,1}
          P.u[1] = par ? hi1x : lo1;   // + {2,3}
          P.u[2] = par ? hi0  : lo0x;  // + {4,5}
          P.u[3] = par ? hi1  : lo1x;  // + {6,7}
          pa[ks2][mt] = P.v;
        }
      }
    }

    // O += P V ; l += P 1  (baseline conflict-free 16x16x32 structure)
#pragma unroll
    for (int ks2 = 0; ks2 < 2; ks2++) {
      f16x8 vb[8];
#pragma unroll
      for (int dt = 0; dt < 8; dt++)
        vb[dt] = *(const f16x8*)(&Vs[(dt * 16 + l16) * 64 + (((ks2 * 4 + quad) ^ (l16 & 7))) * 8]);
#pragma unroll
      for (int mt = 0; mt < 2; mt++) {
#pragma unroll
        for (int dt = 0; dt < 8; dt++)
          Oa[mt][dt] = __builtin_amdgcn_mfma_f32_16x16x32_f16(pa[ks2][mt], vb[dt], Oa[mt][dt], 0, 0, 0);
        lac[mt] = __builtin_amdgcn_mfma_f32_16x16x32_f16(pa[ks2][mt], ones8, lac[mt], 0, 0, 0);
      }
    }

    __syncthreads();   // all Ks/Vs reads done
    if (g + 1 < g1) {
#pragma unroll
      for (int pass = 0; pass < 4; pass++) {
        int r = (t >> 4) + pass * 16;
        *(f16x8*)(&Ks[r * 128 + (((t & 15)) ^ (r & 15)) * 8]) = stK[pass];
      }
#pragma unroll
      for (int pass = 0; pass < 4; pass++) {
        int d = (t >> 3) + pass * 32;
        *(f16x8*)(&Vs[d * 64 + (((t & 7)) ^ (d & 7)) * 8]) = stV[pass];
      }
    }
    __syncthreads();
  }

  // epilogue: unnormalized O + row sums l (C-layout: row q, col d)
  const long rbase = ((long)s * B_ + b) * N_ + qt * 128;
#pragma unroll
  for (int mt = 0; mt < 2; mt++)
#pragma unroll
    for (int rg = 0; rg < 4; rg++) {
      int r = w * 32 + mt * 16 + quad * 4 + rg;
#pragma unroll
      for (int dt = 0; dt < 8; dt++)
        Op[(rbase + r) * C2_ + dt * 16 + l16] = (f16)Oa[mt][dt][rg];
      if (l16 == 0) ls[rbase + r] = lac[mt][rg];
    }
}

// ---------------------------------------------------------------------------
// conv2 + fused NS-split-combine + scale + residual. O view [128][4096]/batch;
// within a (j, pt)-tile the source row q = j*32 + (pt>>1) is constant per j,
// so normalization sum_s(Os)/sum_s(ls) folds into the staging pass.
// Grid (8, 64, 2) -> 4 WG/CU.
// ---------------------------------------------------------------------------
__global__ __launch_bounds__(256, 4)
void conv2_kernel(const f16* __restrict__ Op, const float* __restrict__ ls,
                  const f16* __restrict__ w2h,
                  const float* __restrict__ b2,
                  const float* __restrict__ scale,
                  const float* __restrict__ x,
                  float* __restrict__ out, int ns)
{
  __shared__ f16 Or[128 * 72];      // [j][p_local]
  __shared__ f16 Bsw[64 * 128];     // [p][j] XOR-16
  __shared__ float invL[128];

  const int t = threadIdx.x;
  const int w = t >> 6, lane = t & 63, quad = lane >> 4, l16 = lane & 15;
  const int b = blockIdx.x, pt = blockIdx.y, oh = blockIdx.z;
  const long base0 = (long)b * 524288;            // batch offset within a split

  if (t < 128) {
    int q = t * 32 + (pt >> 1);
    float l = 0.f;
    for (int si = 0; si < ns; si++)
      l += ls[(long)si * 32768 + (long)b * N_ + q];
    invL[t] = 1.0f / fmaxf(l, 1e-20f);
  }
  __syncthreads();

#pragma unroll
  for (int pass = 0; pass < 4; pass++) {
    int j = (t >> 3) + pass * 32;            // 0..127
    int c8 = (t & 7) * 8;                    // p_local
    float fa[8] = {0.f,0.f,0.f,0.f,0.f,0.f,0.f,0.f};
    for (int si = 0; si < ns; si++) {
      f16x8 a = *(const f16x8*)(Op + (long)si * 4194304 + base0 + (long)j * N_ + pt * 64 + c8);
#pragma unroll
      for (int jj = 0; jj < 8; jj++) fa[jj] += (float)a[jj];
    }
    float iv = invL[j];
    f16x8 r;
#pragma unroll
    for (int jj = 0; jj < 8; jj++)
      r[jj] = (f16)(fa[jj] * iv);
    *(f16x8*)(&Or[j * 72 + c8]) = r;
  }
  __syncthreads();
#pragma unroll
  for (int pass = 0; pass < 4; pass++) {
    int p = t & 63;
    int q = (t >> 6) + pass * 4;             // j-block 0..15
    f16x8 vv;
#pragma unroll
    for (int jj = 0; jj < 8; jj++) vv[jj] = Or[(q * 8 + jj) * 72 + p];
    *(f16x8*)(&Bsw[p * 128 + ((q ^ (p & 15))) * 8]) = vv;
  }
  __syncthreads();

  f32x4 acc[2][4];
#pragma unroll
  for (int i = 0; i < 2; i++)
#pragma unroll
    for (int j = 0; j < 4; j++) acc[i][j] = (f32x4){0.f, 0.f, 0.f, 0.f};

#pragma unroll
  for (int ks = 0; ks < 4; ks++) {
    f16x8 bfr[4];
#pragma unroll
    for (int nt = 0; nt < 4; nt++)
      bfr[nt] = *(const f16x8*)(&Bsw[(nt * 16 + l16) * 128 + (((ks * 4 + quad) ^ l16)) * 8]);
#pragma unroll
    for (int mt = 0; mt < 2; mt++) {
      int o = oh * 128 + w * 32 + mt * 16 + l16;
      f16x8 ah = *(const f16x8*)(w2h + o * C2_ + ks * 32 + quad * 8);
#pragma unroll
      for (int nt = 0; nt < 4; nt++)
        acc[mt][nt] = __builtin_amdgcn_mfma_f32_16x16x32_f16(ah, bfr[nt], acc[mt][nt], 0, 0, 0);
    }
  }
#pragma unroll
  for (int mt = 0; mt < 2; mt++)
#pragma unroll
    for (int rg = 0; rg < 4; rg++) {
      int o = oh * 128 + w * 32 + mt * 16 + quad * 4 + rg;
      float so = scale[o], bo = b2[o];
#pragma unroll
      for (int nt = 0; nt < 4; nt++) {
        int p = pt * 64 + nt * 16 + l16;
        long xo = ((long)b * C_ + o) * N_ + p;
        out[xo] = (acc[mt][nt][rg] + bo) * so + x[xo];
      }
    }
}

extern "C" void kernel_launch(void* const* d_in, const int* in_sizes, int n_in,
                              void* d_out, int out_size, void* d_ws, size_t ws_size,
                              hipStream_t stream) {
  const float* x     = (const float*)d_in[0];
  const float* W1    = (const float*)d_in[1];
  const float* b1    = (const float*)d_in[2];
  const float* W2    = (const float*)d_in[3];
  const float* b2    = (const float*)d_in[4];
  const float* scale = (const float*)d_in[5];
  float* outp = (float*)d_out;

  const size_t NE = (size_t)B_ * N_ * C2_;       // 4,194,304

  // pick the largest split count that fits the workspace:
  //   Y + Yt (16 MiB) + ns*Op (8 MiB ea) + ns*ls (128 KiB ea) + w1h/w2h (128 KiB)
  int ns = 4;
  while (ns > 2) {
    size_t need = (size_t)(2 + ns) * NE * 2 + (size_t)ns * (B_ * N_ * 4) + 131072;
    if (need <= ws_size) break;
    ns--;
  }

  f16* Y   = (f16*)d_ws;                         // 8 MiB
  f16* Yt  = Y + NE;                             // 8 MiB
  f16* Op  = Yt + NE;                            // ns x 8 MiB (unnormalized)
  float* ls = (float*)(Op + (size_t)ns * NE);    // ns x 32768 f32 row sums
  f16* w1h = (f16*)(ls + (size_t)ns * 32768);
  f16* w2h = w1h + 32768;

  prep_kernel <<<dim3(128),       dim3(256), 0, stream>>>(W1, W2, w1h, w2h);
  conv1_kernel<<<dim3(8, 128),    dim3(256), 0, stream>>>(x, w1h, b1, Y, Yt);
  attn_kernel <<<dim3(8, 32, ns), dim3(256), 0, stream>>>(Y, Yt, Op, ls);
  conv2_kernel<<<dim3(8, 64, 2),  dim3(256), 0, stream>>>(Op, ls, w2h, b2, scale, x, outp, ns);
}

// Round 5
// 217.833 us; speedup vs baseline: 2.0644x; 2.0644x over previous
//
#include <hip/hip_runtime.h>

#define B_  8
#define C_  256
#define C2_ 128
#define N_  4096
#define LOG2E 1.44269504088896f

typedef _Float16 f16;
typedef _Float16 f16x8 __attribute__((ext_vector_type(8)));
typedef float f32x4  __attribute__((ext_vector_type(4)));

static __device__ __forceinline__ unsigned pk2(float a, float b) {
  return __builtin_bit_cast(unsigned, __builtin_amdgcn_cvt_pkrtz(a, b));  // v_cvt_pkrtz_f16_f32
}

// ---------------------------------------------------------------------------
// prep: cast W1/W2 to f16 once (32768 elements each)
// ---------------------------------------------------------------------------
__global__ __launch_bounds__(256)
void prep_kernel(const float* __restrict__ W1, const float* __restrict__ W2,
                 f16* __restrict__ w1h, f16* __restrict__ w2h)
{
  int i = blockIdx.x * 256 + threadIdx.x;   // grid 128 -> 32768
  w1h[i] = (f16)W1[i];
  w2h[i] = (f16)W2[i];
}

// ---------------------------------------------------------------------------
// conv1: Y[b,n,c2] = sum_c x[b,c,n]*W1[c2,c] + b1; dual layout Y + Yt.
// (unchanged from verified baseline)
// ---------------------------------------------------------------------------
__global__ __launch_bounds__(256, 3)
void conv1_kernel(const float* __restrict__ x,
                  const f16* __restrict__ w1h,
                  const float* __restrict__ b1,
                  f16* __restrict__ Y, f16* __restrict__ Yt)
{
  __shared__ __align__(16) char smem[49152];
  float* Xr = (float*)smem;            // [256 c][32 n] f32, float4-block XOR (32 KB)
  f16*   Ah = (f16*)(smem + 32768);    // [32 n][256 k] f16 XOR-8 (16 KB)
  f16*   T  = (f16*)smem;              // [128 c2][40 n] epilogue alias

  const int t = threadIdx.x;
  const int w = t >> 6, lane = t & 63, quad = lane >> 4, l16 = lane & 15;
  const int b = blockIdx.x, nt0 = blockIdx.y;

  // stage all 256c x 32n fp32 (8 outstanding float4 loads)
#pragma unroll
  for (int pass = 0; pass < 8; pass++) {
    int c  = (t >> 3) + pass * 32;            // 0..255
    int n4 = t & 7;
    float4 v = *(const float4*)(x + ((long)(b * C_ + c)) * N_ + nt0 * 32 + n4 * 4);
    *(float4*)(&Xr[c * 32 + (n4 ^ (c & 7)) * 4]) = v;
  }
  __syncthreads();
  // transpose+cvt into Ah [n][k] XOR-8
#pragma unroll
  for (int pass = 0; pass < 4; pass++) {
    int n  = t & 31;
    int kb = (t >> 5) + pass * 8;             // 0..31
    f16x8 vh;
#pragma unroll
    for (int jj = 0; jj < 8; jj++) {
      int cc = kb * 8 + jj;
      vh[jj] = (f16)Xr[cc * 32 + ((n >> 2) ^ (cc & 7)) * 4 + (n & 3)];
    }
    *(f16x8*)(&Ah[n * 256 + (kb ^ (n & 7)) * 8]) = vh;
  }
  __syncthreads();

  // B-frags from global (L2-hot, shared by all WGs)
  f16x8 bh[2][8];
#pragma unroll
  for (int nt = 0; nt < 2; nt++) {
    int c2 = w * 32 + nt * 16 + l16;
#pragma unroll
    for (int ks = 0; ks < 8; ks++)
      bh[nt][ks] = *(const f16x8*)(w1h + c2 * C_ + ks * 32 + quad * 8);
  }

  f32x4 acc[2][2];
#pragma unroll
  for (int i = 0; i < 2; i++)
#pragma unroll
    for (int j = 0; j < 2; j++) acc[i][j] = (f32x4){0.f, 0.f, 0.f, 0.f};

#pragma unroll
  for (int ks = 0; ks < 8; ks++)
#pragma unroll
    for (int mt = 0; mt < 2; mt++) {
      f16x8 ah = *(const f16x8*)(&Ah[(mt * 16 + l16) * 256 + (((ks * 4 + quad) ^ (l16 & 7))) * 8]);
#pragma unroll
      for (int nt = 0; nt < 2; nt++)
        acc[mt][nt] = __builtin_amdgcn_mfma_f32_16x16x32_f16(ah, bh[nt][ks], acc[mt][nt], 0, 0, 0);
    }
  __syncthreads();   // Xr dead -> T alias safe

  // epilogue -> T[c2][n]
#pragma unroll
  for (int nt = 0; nt < 2; nt++) {
    int c2 = w * 32 + nt * 16 + l16;
    float bv = b1[c2];
#pragma unroll
    for (int mt = 0; mt < 2; mt++)
#pragma unroll
      for (int rg = 0; rg < 4; rg++) {
        int n = mt * 16 + quad * 4 + rg;
        T[c2 * 40 + n] = (f16)(acc[mt][nt][rg] + bv);
      }
  }
  __syncthreads();
  // Yt[c2][n]: vec8 along n
#pragma unroll
  for (int pass = 0; pass < 2; pass++) {
    int r  = (t >> 2) + pass * 64;            // c2 0..127
    int c8 = (t & 3) * 8;                     // n
    f16x8 v = *(const f16x8*)(&T[r * 40 + c8]);
    *(f16x8*)(Yt + ((long)(b * C2_ + r)) * N_ + nt0 * 32 + c8) = v;
  }
  // Y[n][c2]: gather
#pragma unroll
  for (int pass = 0; pass < 2; pass++) {
    int row = t & 31;
    int cg  = (t >> 5) + pass * 8;            // c2-block 0..15
    f16x8 v;
#pragma unroll
    for (int jj = 0; jj < 8; jj++) v[jj] = T[(cg * 8 + jj) * 40 + row];
    *(f16x8*)(Y + ((long)(b * N_ + nt0 * 32 + row)) * C2_ + cg * 8) = v;
  }
}

// ---------------------------------------------------------------------------
// attn v5: v3 structure (swapped QK^T, register P via permlane32_swap +
// ds_swizzle exchange, conflict-free 16x16x32 PV) with NS-way split-K.
// Grid (8, 32, NS); NS=4 -> 1024 blocks = 4 WG/CU.
// launch_bounds(256,2): R2-verified codegen (120 VGPR, no spill). VGPR 120
// <= 128 already permits the 4-blocks/CU tier; (256,4) forced 64 VGPR +
// catastrophic scratch spill (R4: 717 MB FETCH). Do not tighten it.
// ---------------------------------------------------------------------------
__global__ __launch_bounds__(256, 2)
void attn_kernel(const f16* __restrict__ Y, const f16* __restrict__ Yt,
                 f16* __restrict__ Op, float* __restrict__ ls)
{
  __shared__ f16 Ks[64 * 128];   // [key][d]  16B-block pos = (d>>3) ^ (key&15)
  __shared__ f16 Vs[128 * 64];   // [d][k]    pos = (k>>3) ^ (d&7)
  __shared__ float nsqf[128];

  const int t = threadIdx.x;
  const int w = t >> 6, lane = t & 63, quad = lane >> 4, l16 = lane & 15;
  const int b = blockIdx.x, qt = blockIdx.y, s = blockIdx.z;
  const int ns = gridDim.z;
  const f16* Yb  = Y  + (long)b * N_ * C2_;
  const f16* Ytb = Yt + (long)b * C2_ * N_;
  const int g0 = (s * 64) / ns;        // first 64-key tile of this split
  const int g1 = ((s + 1) * 64) / ns;  // one past last

  // Q frags (A/B-frag layout identical for 16x16x32): row q=l16, d-chunk quad*8
  f16x8 qf[2][4];
#pragma unroll
  for (int mt = 0; mt < 2; mt++)
#pragma unroll
    for (int ks = 0; ks < 4; ks++)
      qf[mt][ks] = *(const f16x8*)(Yb + (long)(qt * 128 + w * 32 + mt * 16 + l16) * C2_ + ks * 32 + quad * 8);

  // per-row |y_q|^2 (exact same f16 values the MFMA sees)
  {
    int r = t >> 1, half = t & 1;
    float ss = 0.f;
#pragma unroll
    for (int j = 0; j < 8; j++) {
      f16x8 v = *(const f16x8*)(Yb + (long)(qt * 128 + r) * C2_ + half * 64 + j * 8);
#pragma unroll
      for (int e = 0; e < 8; e++) { float f = (float)v[e]; ss = fmaf(f, f, ss); }
    }
    ss += __shfl_xor(ss, 1);
    if (!half) nsqf[r] = ss;
  }

  // prologue: stage first tile of this split
  {
    const int kb0 = g0 * 64;
#pragma unroll
    for (int pass = 0; pass < 4; pass++) {
      int r = (t >> 4) + pass * 16;
      f16x8 kv = *(const f16x8*)(Yb + (long)(kb0 + r) * C2_ + (t & 15) * 8);
      *(f16x8*)(&Ks[r * 128 + (((t & 15)) ^ (r & 15)) * 8]) = kv;
    }
#pragma unroll
    for (int pass = 0; pass < 4; pass++) {
      int d = (t >> 3) + pass * 32;
      f16x8 vv = *(const f16x8*)(Ytb + (long)d * N_ + kb0 + (t & 7) * 8);
      *(f16x8*)(&Vs[d * 64 + (((t & 7)) ^ (d & 7)) * 8]) = vv;
    }
  }
  __syncthreads();

  // fixed per-row max (log2 units), per-lane by q=l16
  float nm[2];
  nm[0] = nsqf[w * 32 + l16] * LOG2E;
  nm[1] = nsqf[w * 32 + 16 + l16] * LOG2E;

  f16x8 ones8;
#pragma unroll
  for (int j = 0; j < 8; j++) ones8[j] = (f16)1.0f;

  f32x4 Oa[2][8];                 // C-layout: row q = quad*4+rg, col d = l16
#pragma unroll
  for (int i = 0; i < 2; i++)
#pragma unroll
    for (int j = 0; j < 8; j++) Oa[i][j] = (f32x4){0.f, 0.f, 0.f, 0.f};
  f32x4 lac[2] = {(f32x4){0.f,0.f,0.f,0.f}, (f32x4){0.f,0.f,0.f,0.f}};

#pragma unroll 1
  for (int g = g0; g < g1; g++) {
    // prefetch next tile into registers
    f16x8 stK[4], stV[4];
    if (g + 1 < g1) {
      int nb = (g + 1) * 64;
#pragma unroll
      for (int pass = 0; pass < 4; pass++)
        stK[pass] = *(const f16x8*)(Yb + (long)(nb + (t >> 4) + pass * 16) * C2_ + (t & 15) * 8);
#pragma unroll
      for (int pass = 0; pass < 4; pass++)
        stV[pass] = *(const f16x8*)(Ytb + (long)((t >> 3) + pass * 32) * N_ + nb + (t & 7) * 8);
    }

    // S^T = K Q^T : row = key(quad*4+rg within nt), col = q(l16)
    f32x4 S[4][2];
#pragma unroll
    for (int i = 0; i < 4; i++)
#pragma unroll
      for (int j = 0; j < 2; j++) S[i][j] = (f32x4){0.f, 0.f, 0.f, 0.f};
#pragma unroll
    for (int ks = 0; ks < 4; ks++) {
      f16x8 bfr[4];
#pragma unroll
      for (int nt = 0; nt < 4; nt++)
        bfr[nt] = *(const f16x8*)(&Ks[(nt * 16 + l16) * 128 + (((ks * 4 + quad) ^ l16)) * 8]);
#pragma unroll
      for (int nt = 0; nt < 4; nt++)
#pragma unroll
        for (int mt = 0; mt < 2; mt++)
          S[nt][mt] = __builtin_amdgcn_mfma_f32_16x16x32_f16(bfr[nt], qf[mt][ks], S[nt][mt], 0, 0, 0);
    }

    // fixed-max exp -> packed f16 pairs: Xp[mt][nt][d] = keys quad*4+{2d,2d+1}
    unsigned Xp[2][4][2];
#pragma unroll
    for (int mt = 0; mt < 2; mt++)
#pragma unroll
      for (int nt = 0; nt < 4; nt++) {
        float p0 = exp2f(fminf(fmaf(S[nt][mt][0], LOG2E, -nm[mt]), 11.0f));
        float p1 = exp2f(fminf(fmaf(S[nt][mt][1], LOG2E, -nm[mt]), 11.0f));
        float p2 = exp2f(fminf(fmaf(S[nt][mt][2], LOG2E, -nm[mt]), 11.0f));
        float p3 = exp2f(fminf(fmaf(S[nt][mt][3], LOG2E, -nm[mt]), 11.0f));
        Xp[mt][nt][0] = pk2(p0, p1);
        Xp[mt][nt][1] = pk2(p2, p3);
      }

    // register exchange -> PV A-frags pa[ks2][mt] (P[q=l16][k=quad*8..+7])
    f16x8 pa[2][2];
    {
      const bool par = (quad & 1) != 0;
#pragma unroll
      for (int mt = 0; mt < 2; mt++) {
#pragma unroll
        for (int pr = 0; pr < 2; pr++)
#pragma unroll
          for (int d = 0; d < 2; d++) {
            auto r = __builtin_amdgcn_permlane32_swap(Xp[mt][2 * pr][d], Xp[mt][2 * pr + 1][d], false, false);
            Xp[mt][2 * pr][d]     = r[0];   // src quads 0,1 (nt pr*2 lo half, pr*2+1 hi half)
            Xp[mt][2 * pr + 1][d] = r[1];   // src quads 2,3
          }
#pragma unroll
        for (int ks2 = 0; ks2 < 2; ks2++) {
          unsigned lo0 = Xp[mt][2 * ks2][0],     lo1 = Xp[mt][2 * ks2][1];
          unsigned hi0 = Xp[mt][2 * ks2 + 1][0], hi1 = Xp[mt][2 * ks2 + 1][1];
          unsigned lo0x = (unsigned)__builtin_amdgcn_ds_swizzle((int)lo0, 0x401F);  // xor 16
          unsigned lo1x = (unsigned)__builtin_amdgcn_ds_swizzle((int)lo1, 0x401F);
          unsigned hi0x = (unsigned)__builtin_amdgcn_ds_swizzle((int)hi0, 0x401F);
          unsigned hi1x = (unsigned)__builtin_amdgcn_ds_swizzle((int)hi1, 0x401F);
          union { unsigned u[4]; f16x8 v; } P;
          P.u[0] = par ? hi0x : lo0;   // k quad*8 + {0,1}
          P.u[1] = par ? hi1x : lo1;   // + {2,3}
          P.u[2] = par ? hi0  : lo0x;  // + {4,5}
          P.u[3] = par ? hi1  : lo1x;  // + {6,7}
          pa[ks2][mt] = P.v;
        }
      }
    }

    // O += P V ; l += P 1  (conflict-free 16x16x32 structure)
#pragma unroll
    for (int ks2 = 0; ks2 < 2; ks2++) {
      f16x8 vb[8];
#pragma unroll
      for (int dt = 0; dt < 8; dt++)
        vb[dt] = *(const f16x8*)(&Vs[(dt * 16 + l16) * 64 + (((ks2 * 4 + quad) ^ (l16 & 7))) * 8]);
#pragma unroll
      for (int mt = 0; mt < 2; mt++) {
#pragma unroll
        for (int dt = 0; dt < 8; dt++)
          Oa[mt][dt] = __builtin_amdgcn_mfma_f32_16x16x32_f16(pa[ks2][mt], vb[dt], Oa[mt][dt], 0, 0, 0);
        lac[mt] = __builtin_amdgcn_mfma_f32_16x16x32_f16(pa[ks2][mt], ones8, lac[mt], 0, 0, 0);
      }
    }

    __syncthreads();   // all Ks/Vs reads done
    if (g + 1 < g1) {
#pragma unroll
      for (int pass = 0; pass < 4; pass++) {
        int r = (t >> 4) + pass * 16;
        *(f16x8*)(&Ks[r * 128 + (((t & 15)) ^ (r & 15)) * 8]) = stK[pass];
      }
#pragma unroll
      for (int pass = 0; pass < 4; pass++) {
        int d = (t >> 3) + pass * 32;
        *(f16x8*)(&Vs[d * 64 + (((t & 7)) ^ (d & 7)) * 8]) = stV[pass];
      }
    }
    __syncthreads();
  }

  // epilogue: unnormalized O + row sums l (C-layout: row q, col d)
  const long rbase = ((long)s * B_ + b) * N_ + qt * 128;
#pragma unroll
  for (int mt = 0; mt < 2; mt++)
#pragma unroll
    for (int rg = 0; rg < 4; rg++) {
      int r = w * 32 + mt * 16 + quad * 4 + rg;
#pragma unroll
      for (int dt = 0; dt < 8; dt++)
        Op[(rbase + r) * C2_ + dt * 16 + l16] = (f16)Oa[mt][dt][rg];
      if (l16 == 0) ls[rbase + r] = lac[mt][rg];
    }
}

// ---------------------------------------------------------------------------
// conv2 + fused NS-split-combine + scale + residual. O view [128][4096]/batch;
// within a (j, pt)-tile the source row q = j*32 + (pt>>1) is constant per j,
// so normalization sum_s(Os)/sum_s(ls) folds into the staging pass.
// Grid (8, 64, 2) -> 4 WG/CU.
// ---------------------------------------------------------------------------
__global__ __launch_bounds__(256, 4)
void conv2_kernel(const f16* __restrict__ Op, const float* __restrict__ ls,
                  const f16* __restrict__ w2h,
                  const float* __restrict__ b2,
                  const float* __restrict__ scale,
                  const float* __restrict__ x,
                  float* __restrict__ out, int ns)
{
  __shared__ f16 Or[128 * 72];      // [j][p_local]
  __shared__ f16 Bsw[64 * 128];     // [p][j] XOR-16
  __shared__ float invL[128];

  const int t = threadIdx.x;
  const int w = t >> 6, lane = t & 63, quad = lane >> 4, l16 = lane & 15;
  const int b = blockIdx.x, pt = blockIdx.y, oh = blockIdx.z;
  const long base0 = (long)b * 524288;            // batch offset within a split

  if (t < 128) {
    int q = t * 32 + (pt >> 1);
    float l = 0.f;
    for (int si = 0; si < ns; si++)
      l += ls[(long)si * 32768 + (long)b * N_ + q];
    invL[t] = 1.0f / fmaxf(l, 1e-20f);
  }
  __syncthreads();

#pragma unroll
  for (int pass = 0; pass < 4; pass++) {
    int j = (t >> 3) + pass * 32;            // 0..127
    int c8 = (t & 7) * 8;                    // p_local
    float fa[8] = {0.f,0.f,0.f,0.f,0.f,0.f,0.f,0.f};
    for (int si = 0; si < ns; si++) {
      f16x8 a = *(const f16x8*)(Op + (long)si * 4194304 + base0 + (long)j * N_ + pt * 64 + c8);
#pragma unroll
      for (int jj = 0; jj < 8; jj++) fa[jj] += (float)a[jj];
    }
    float iv = invL[j];
    f16x8 r;
#pragma unroll
    for (int jj = 0; jj < 8; jj++)
      r[jj] = (f16)(fa[jj] * iv);
    *(f16x8*)(&Or[j * 72 + c8]) = r;
  }
  __syncthreads();
#pragma unroll
  for (int pass = 0; pass < 4; pass++) {
    int p = t & 63;
    int q = (t >> 6) + pass * 4;             // j-block 0..15
    f16x8 vv;
#pragma unroll
    for (int jj = 0; jj < 8; jj++) vv[jj] = Or[(q * 8 + jj) * 72 + p];
    *(f16x8*)(&Bsw[p * 128 + ((q ^ (p & 15))) * 8]) = vv;
  }
  __syncthreads();

  f32x4 acc[2][4];
#pragma unroll
  for (int i = 0; i < 2; i++)
#pragma unroll
    for (int j = 0; j < 4; j++) acc[i][j] = (f32x4){0.f, 0.f, 0.f, 0.f};

#pragma unroll
  for (int ks = 0; ks < 4; ks++) {
    f16x8 bfr[4];
#pragma unroll
    for (int nt = 0; nt < 4; nt++)
      bfr[nt] = *(const f16x8*)(&Bsw[(nt * 16 + l16) * 128 + (((ks * 4 + quad) ^ l16)) * 8]);
#pragma unroll
    for (int mt = 0; mt < 2; mt++) {
      int o = oh * 128 + w * 32 + mt * 16 + l16;
      f16x8 ah = *(const f16x8*)(w2h + o * C2_ + ks * 32 + quad * 8);
#pragma unroll
      for (int nt = 0; nt < 4; nt++)
        acc[mt][nt] = __builtin_amdgcn_mfma_f32_16x16x32_f16(ah, bfr[nt], acc[mt][nt], 0, 0, 0);
    }
  }
#pragma unroll
  for (int mt = 0; mt < 2; mt++)
#pragma unroll
    for (int rg = 0; rg < 4; rg++) {
      int o = oh * 128 + w * 32 + mt * 16 + quad * 4 + rg;
      float so = scale[o], bo = b2[o];
#pragma unroll
      for (int nt = 0; nt < 4; nt++) {
        int p = pt * 64 + nt * 16 + l16;
        long xo = ((long)b * C_ + o) * N_ + p;
        out[xo] = (acc[mt][nt][rg] + bo) * so + x[xo];
      }
    }
}

extern "C" void kernel_launch(void* const* d_in, const int* in_sizes, int n_in,
                              void* d_out, int out_size, void* d_ws, size_t ws_size,
                              hipStream_t stream) {
  const float* x     = (const float*)d_in[0];
  const float* W1    = (const float*)d_in[1];
  const float* b1    = (const float*)d_in[2];
  const float* W2    = (const float*)d_in[3];
  const float* b2    = (const float*)d_in[4];
  const float* scale = (const float*)d_in[5];
  float* outp = (float*)d_out;

  const size_t NE = (size_t)B_ * N_ * C2_;       // 4,194,304

  // pick the largest split count that fits the workspace:
  //   Y + Yt (16 MiB) + ns*Op (8 MiB ea) + ns*ls (128 KiB ea) + w1h/w2h (128 KiB)
  int ns = 4;
  while (ns > 2) {
    size_t need = (size_t)(2 + ns) * NE * 2 + (size_t)ns * (B_ * N_ * 4) + 131072;
    if (need <= ws_size) break;
    ns--;
  }

  f16* Y   = (f16*)d_ws;                         // 8 MiB
  f16* Yt  = Y + NE;                             // 8 MiB
  f16* Op  = Yt + NE;                            // ns x 8 MiB (unnormalized)
  float* ls = (float*)(Op + (size_t)ns * NE);    // ns x 32768 f32 row sums
  f16* w1h = (f16*)(ls + (size_t)ns * 32768);
  f16* w2h = w1h + 32768;

  prep_kernel <<<dim3(128),       dim3(256), 0, stream>>>(W1, W2, w1h, w2h);
  conv1_kernel<<<dim3(8, 128),    dim3(256), 0, stream>>>(x, w1h, b1, Y, Yt);
  attn_kernel <<<dim3(8, 32, ns), dim3(256), 0, stream>>>(Y, Yt, Op, ls);
  conv2_kernel<<<dim3(8, 64, 2),  dim3(256), 0, stream>>>(Op, ls, w2h, b2, scale, x, outp, ns);
}

// Round 6
// 211.977 us; speedup vs baseline: 2.1214x; 1.0276x over previous
//
#include <hip/hip_runtime.h>

#define B_  8
#define C_  256
#define C2_ 128
#define N_  4096
#define LOG2E 1.44269504088896f

typedef _Float16 f16;
typedef _Float16 f16x8 __attribute__((ext_vector_type(8)));
typedef float f32x4  __attribute__((ext_vector_type(4)));

static __device__ __forceinline__ unsigned pk2(float a, float b) {
  return __builtin_bit_cast(unsigned, __builtin_amdgcn_cvt_pkrtz(a, b));  // v_cvt_pkrtz_f16_f32
}

// ---------------------------------------------------------------------------
// prep: cast W1/W2 to f16 once (32768 elements each)
// ---------------------------------------------------------------------------
__global__ __launch_bounds__(256)
void prep_kernel(const float* __restrict__ W1, const float* __restrict__ W2,
                 f16* __restrict__ w1h, f16* __restrict__ w2h)
{
  int i = blockIdx.x * 256 + threadIdx.x;   // grid 128 -> 32768
  w1h[i] = (f16)W1[i];
  w2h[i] = (f16)W2[i];
}

// ---------------------------------------------------------------------------
// conv1: Y[b,n,c2] = sum_c x[b,c,n]*W1[c2,c] + b1; dual layout Y + Yt.
// (unchanged from verified baseline)
// ---------------------------------------------------------------------------
__global__ __launch_bounds__(256, 3)
void conv1_kernel(const float* __restrict__ x,
                  const f16* __restrict__ w1h,
                  const float* __restrict__ b1,
                  f16* __restrict__ Y, f16* __restrict__ Yt)
{
  __shared__ __align__(16) char smem[49152];
  float* Xr = (float*)smem;            // [256 c][32 n] f32, float4-block XOR (32 KB)
  f16*   Ah = (f16*)(smem + 32768);    // [32 n][256 k] f16 XOR-8 (16 KB)
  f16*   T  = (f16*)smem;              // [128 c2][40 n] epilogue alias

  const int t = threadIdx.x;
  const int w = t >> 6, lane = t & 63, quad = lane >> 4, l16 = lane & 15;
  const int b = blockIdx.x, nt0 = blockIdx.y;

  // stage all 256c x 32n fp32 (8 outstanding float4 loads)
#pragma unroll
  for (int pass = 0; pass < 8; pass++) {
    int c  = (t >> 3) + pass * 32;            // 0..255
    int n4 = t & 7;
    float4 v = *(const float4*)(x + ((long)(b * C_ + c)) * N_ + nt0 * 32 + n4 * 4);
    *(float4*)(&Xr[c * 32 + (n4 ^ (c & 7)) * 4]) = v;
  }
  __syncthreads();
  // transpose+cvt into Ah [n][k] XOR-8
#pragma unroll
  for (int pass = 0; pass < 4; pass++) {
    int n  = t & 31;
    int kb = (t >> 5) + pass * 8;             // 0..31
    f16x8 vh;
#pragma unroll
    for (int jj = 0; jj < 8; jj++) {
      int cc = kb * 8 + jj;
      vh[jj] = (f16)Xr[cc * 32 + ((n >> 2) ^ (cc & 7)) * 4 + (n & 3)];
    }
    *(f16x8*)(&Ah[n * 256 + (kb ^ (n & 7)) * 8]) = vh;
  }
  __syncthreads();

  // B-frags from global (L2-hot, shared by all WGs)
  f16x8 bh[2][8];
#pragma unroll
  for (int nt = 0; nt < 2; nt++) {
    int c2 = w * 32 + nt * 16 + l16;
#pragma unroll
    for (int ks = 0; ks < 8; ks++)
      bh[nt][ks] = *(const f16x8*)(w1h + c2 * C_ + ks * 32 + quad * 8);
  }

  f32x4 acc[2][2];
#pragma unroll
  for (int i = 0; i < 2; i++)
#pragma unroll
    for (int j = 0; j < 2; j++) acc[i][j] = (f32x4){0.f, 0.f, 0.f, 0.f};

#pragma unroll
  for (int ks = 0; ks < 8; ks++)
#pragma unroll
    for (int mt = 0; mt < 2; mt++) {
      f16x8 ah = *(const f16x8*)(&Ah[(mt * 16 + l16) * 256 + (((ks * 4 + quad) ^ (l16 & 7))) * 8]);
#pragma unroll
      for (int nt = 0; nt < 2; nt++)
        acc[mt][nt] = __builtin_amdgcn_mfma_f32_16x16x32_f16(ah, bh[nt][ks], acc[mt][nt], 0, 0, 0);
    }
  __syncthreads();   // Xr dead -> T alias safe

  // epilogue -> T[c2][n]
#pragma unroll
  for (int nt = 0; nt < 2; nt++) {
    int c2 = w * 32 + nt * 16 + l16;
    float bv = b1[c2];
#pragma unroll
    for (int mt = 0; mt < 2; mt++)
#pragma unroll
      for (int rg = 0; rg < 4; rg++) {
        int n = mt * 16 + quad * 4 + rg;
        T[c2 * 40 + n] = (f16)(acc[mt][nt][rg] + bv);
      }
  }
  __syncthreads();
  // Yt[c2][n]: vec8 along n
#pragma unroll
  for (int pass = 0; pass < 2; pass++) {
    int r  = (t >> 2) + pass * 64;            // c2 0..127
    int c8 = (t & 3) * 8;                     // n
    f16x8 v = *(const f16x8*)(&T[r * 40 + c8]);
    *(f16x8*)(Yt + ((long)(b * C2_ + r)) * N_ + nt0 * 32 + c8) = v;
  }
  // Y[n][c2]: gather
#pragma unroll
  for (int pass = 0; pass < 2; pass++) {
    int row = t & 31;
    int cg  = (t >> 5) + pass * 8;            // c2-block 0..15
    f16x8 v;
#pragma unroll
    for (int jj = 0; jj < 8; jj++) v[jj] = T[(cg * 8 + jj) * 40 + row];
    *(f16x8*)(Y + ((long)(b * N_ + nt0 * 32 + row)) * C2_ + cg * 8) = v;
  }
}

// ---------------------------------------------------------------------------
// attn v6: swapped QK^T + register-P (verified R2/R5 math, bit-identical) with
//  (1) DOUBLE-BUFFERED K/V LDS -> ONE barrier per K-tile (was 2). Iter g:
//      issue loads g+1 -> compute from buf[p] -> write buf[p^1] -> barrier.
//      The write/read race on buf[p^1] vs iter g-1 is split by that barrier.
//  (2) loop-invariant LDS addresses: XOR terms split on disjoint bit-fields
//      ((ks*4+quad)^l16 = (ks*4 ^ (l16&12)) | (quad ^ (l16&3))), so all
//      read/write addresses = per-lane base (precomputed) + const offset.
// LDS 64.5 KB; residency is VGPR-capped at 2 WG/CU anyway (arch+acc ~230/wave
// -> 2 waves/SIMD; R4/R5 evidence), so the extra LDS is free.
// launch_bounds(256,2): do NOT tighten (R4: forced 64 VGPR = 717 MB spill).
// ---------------------------------------------------------------------------
__global__ __launch_bounds__(256, 2)
void attn_kernel(const f16* __restrict__ Y, const f16* __restrict__ Yt,
                 f16* __restrict__ Op, float* __restrict__ ls)
{
  __shared__ f16 Ks[2][64 * 128];   // [key][d]  16B-block pos = (d>>3) ^ (key&15)
  __shared__ f16 Vs[2][128 * 64];   // [d][k]    pos = (k>>3) ^ (d&7)
  __shared__ float nsqf[128];

  const int t = threadIdx.x;
  const int w = t >> 6, lane = t & 63, quad = lane >> 4, l16 = lane & 15;
  const int b = blockIdx.x, qt = blockIdx.y, s = blockIdx.z;
  const int ns = gridDim.z;
  const f16* Yb  = Y  + (long)b * N_ * C2_;
  const f16* Ytb = Yt + (long)b * C2_ * N_;
  const int g0 = (s * 64) / ns;        // first 64-key tile of this split
  const int g1 = ((s + 1) * 64) / ns;  // one past last

  // loop-invariant per-lane LDS bases (element offsets are compile-time)
  const int l3 = l16 & 3, l12 = l16 & 12, l4v = l16 & 4;
  const f16* kp[4];                    // QK^T: read kp[ks] + cur*8192 + nt*2048
#pragma unroll
  for (int ks = 0; ks < 4; ks++)
    kp[ks] = &Ks[0][l16 * 128 + (((ks * 4) ^ l12) + (quad ^ l3)) * 8];
  const f16* vp[2];                    // PV:  read vp[ks2] + cur*8192 + dt*1024
#pragma unroll
  for (int ks2 = 0; ks2 < 2; ks2++)
    vp[ks2] = &Vs[0][l16 * 64 + (((ks2 * 4) ^ l4v) + (quad ^ l3)) * 8];
  f16* kwp = &Ks[0][(t >> 4) * 128 + ((t & 15) ^ (t >> 4)) * 8];        // + pass*2048
  f16* vwp = &Vs[0][(t >> 3) * 64 + ((t & 7) ^ ((t >> 3) & 7)) * 8];    // + pass*2048

  // Q frags (A/B-frag layout identical for 16x16x32): row q=l16, d-chunk quad*8
  f16x8 qf[2][4];
#pragma unroll
  for (int mt = 0; mt < 2; mt++)
#pragma unroll
    for (int ks = 0; ks < 4; ks++)
      qf[mt][ks] = *(const f16x8*)(Yb + (long)(qt * 128 + w * 32 + mt * 16 + l16) * C2_ + ks * 32 + quad * 8);

  // per-row |y_q|^2 (exact same f16 values the MFMA sees)
  {
    int r = t >> 1, half = t & 1;
    float ss = 0.f;
#pragma unroll
    for (int j = 0; j < 8; j++) {
      f16x8 v = *(const f16x8*)(Yb + (long)(qt * 128 + r) * C2_ + half * 64 + j * 8);
#pragma unroll
      for (int e = 0; e < 8; e++) { float f = (float)v[e]; ss = fmaf(f, f, ss); }
    }
    ss += __shfl_xor(ss, 1);
    if (!half) nsqf[r] = ss;
  }

  // prologue: stage tile g0 into buffer 0
  {
    const int kb0 = g0 * 64;
#pragma unroll
    for (int pass = 0; pass < 4; pass++) {
      f16x8 kv = *(const f16x8*)(Yb + (long)(kb0 + (t >> 4) + pass * 16) * C2_ + (t & 15) * 8);
      *(f16x8*)(kwp + pass * 2048) = kv;
    }
#pragma unroll
    for (int pass = 0; pass < 4; pass++) {
      f16x8 vv = *(const f16x8*)(Ytb + (long)((t >> 3) + pass * 32) * N_ + kb0 + (t & 7) * 8);
      *(f16x8*)(vwp + pass * 2048) = vv;
    }
  }
  __syncthreads();

  // fixed per-row max (log2 units), per-lane by q=l16
  float nm[2];
  nm[0] = nsqf[w * 32 + l16] * LOG2E;
  nm[1] = nsqf[w * 32 + 16 + l16] * LOG2E;

  f16x8 ones8;
#pragma unroll
  for (int j = 0; j < 8; j++) ones8[j] = (f16)1.0f;

  f32x4 Oa[2][8];                 // C-layout: row q = quad*4+rg, col d = l16
#pragma unroll
  for (int i = 0; i < 2; i++)
#pragma unroll
    for (int j = 0; j < 8; j++) Oa[i][j] = (f32x4){0.f, 0.f, 0.f, 0.f};
  f32x4 lac[2] = {(f32x4){0.f,0.f,0.f,0.f}, (f32x4){0.f,0.f,0.f,0.f}};

  int cur = 0;
#pragma unroll 1
  for (int g = g0; g < g1; g++) {
    // issue next-tile global loads first (latency hides under compute)
    f16x8 stK[4], stV[4];
    const bool pf = (g + 1 < g1);
    if (pf) {
      int nb = (g + 1) * 64;
#pragma unroll
      for (int pass = 0; pass < 4; pass++)
        stK[pass] = *(const f16x8*)(Yb + (long)(nb + (t >> 4) + pass * 16) * C2_ + (t & 15) * 8);
#pragma unroll
      for (int pass = 0; pass < 4; pass++)
        stV[pass] = *(const f16x8*)(Ytb + (long)((t >> 3) + pass * 32) * N_ + nb + (t & 7) * 8);
    }
    const int co = cur * 8192;

    // S^T = K Q^T : row = key(quad*4+rg within nt), col = q(l16)
    f32x4 S[4][2];
#pragma unroll
    for (int i = 0; i < 4; i++)
#pragma unroll
      for (int j = 0; j < 2; j++) S[i][j] = (f32x4){0.f, 0.f, 0.f, 0.f};
#pragma unroll
    for (int ks = 0; ks < 4; ks++) {
      f16x8 bfr[4];
#pragma unroll
      for (int nt = 0; nt < 4; nt++)
        bfr[nt] = *(const f16x8*)(kp[ks] + co + nt * 2048);
#pragma unroll
      for (int nt = 0; nt < 4; nt++)
#pragma unroll
        for (int mt = 0; mt < 2; mt++)
          S[nt][mt] = __builtin_amdgcn_mfma_f32_16x16x32_f16(bfr[nt], qf[mt][ks], S[nt][mt], 0, 0, 0);
    }

    // fixed-max exp -> packed f16 pairs: Xp[mt][nt][d] = keys quad*4+{2d,2d+1}
    unsigned Xp[2][4][2];
#pragma unroll
    for (int mt = 0; mt < 2; mt++)
#pragma unroll
      for (int nt = 0; nt < 4; nt++) {
        float p0 = exp2f(fminf(fmaf(S[nt][mt][0], LOG2E, -nm[mt]), 11.0f));
        float p1 = exp2f(fminf(fmaf(S[nt][mt][1], LOG2E, -nm[mt]), 11.0f));
        float p2 = exp2f(fminf(fmaf(S[nt][mt][2], LOG2E, -nm[mt]), 11.0f));
        float p3 = exp2f(fminf(fmaf(S[nt][mt][3], LOG2E, -nm[mt]), 11.0f));
        Xp[mt][nt][0] = pk2(p0, p1);
        Xp[mt][nt][1] = pk2(p2, p3);
      }

    // register exchange -> PV A-frags pa[ks2][mt] (P[q=l16][k=quad*8..+7])
    f16x8 pa[2][2];
    {
      const bool par = (quad & 1) != 0;
#pragma unroll
      for (int mt = 0; mt < 2; mt++) {
#pragma unroll
        for (int pr = 0; pr < 2; pr++)
#pragma unroll
          for (int d = 0; d < 2; d++) {
            auto r = __builtin_amdgcn_permlane32_swap(Xp[mt][2 * pr][d], Xp[mt][2 * pr + 1][d], false, false);
            Xp[mt][2 * pr][d]     = r[0];   // src quads 0,1 (nt pr*2 lo half, pr*2+1 hi half)
            Xp[mt][2 * pr + 1][d] = r[1];   // src quads 2,3
          }
#pragma unroll
        for (int ks2 = 0; ks2 < 2; ks2++) {
          unsigned lo0 = Xp[mt][2 * ks2][0],     lo1 = Xp[mt][2 * ks2][1];
          unsigned hi0 = Xp[mt][2 * ks2 + 1][0], hi1 = Xp[mt][2 * ks2 + 1][1];
          unsigned lo0x = (unsigned)__builtin_amdgcn_ds_swizzle((int)lo0, 0x401F);  // xor 16
          unsigned lo1x = (unsigned)__builtin_amdgcn_ds_swizzle((int)lo1, 0x401F);
          unsigned hi0x = (unsigned)__builtin_amdgcn_ds_swizzle((int)hi0, 0x401F);
          unsigned hi1x = (unsigned)__builtin_amdgcn_ds_swizzle((int)hi1, 0x401F);
          union { unsigned u[4]; f16x8 v; } P;
          P.u[0] = par ? hi0x : lo0;   // k quad*8 + {0,1}
          P.u[1] = par ? hi1x : lo1;   // + {2,3}
          P.u[2] = par ? hi0  : lo0x;  // + {4,5}
          P.u[3] = par ? hi1  : lo1x;  // + {6,7}
          pa[ks2][mt] = P.v;
        }
      }
    }

    // O += P V ; l += P 1  (conflict-free 16x16x32 structure)
#pragma unroll
    for (int ks2 = 0; ks2 < 2; ks2++) {
      f16x8 vb[8];
#pragma unroll
      for (int dt = 0; dt < 8; dt++)
        vb[dt] = *(const f16x8*)(vp[ks2] + co + dt * 1024);
#pragma unroll
      for (int mt = 0; mt < 2; mt++) {
#pragma unroll
        for (int dt = 0; dt < 8; dt++)
          Oa[mt][dt] = __builtin_amdgcn_mfma_f32_16x16x32_f16(pa[ks2][mt], vb[dt], Oa[mt][dt], 0, 0, 0);
        lac[mt] = __builtin_amdgcn_mfma_f32_16x16x32_f16(pa[ks2][mt], ones8, lac[mt], 0, 0, 0);
      }
    }

    // write next tile into the other buffer, single barrier
    if (pf) {
      const int no = (cur ^ 1) * 8192;
#pragma unroll
      for (int pass = 0; pass < 4; pass++)
        *(f16x8*)(kwp + no + pass * 2048) = stK[pass];
#pragma unroll
      for (int pass = 0; pass < 4; pass++)
        *(f16x8*)(vwp + no + pass * 2048) = stV[pass];
      cur ^= 1;
      __syncthreads();
    }
  }

  // epilogue: unnormalized O + row sums l (C-layout: row q, col d)
  const long rbase = ((long)s * B_ + b) * N_ + qt * 128;
#pragma unroll
  for (int mt = 0; mt < 2; mt++)
#pragma unroll
    for (int rg = 0; rg < 4; rg++) {
      int r = w * 32 + mt * 16 + quad * 4 + rg;
#pragma unroll
      for (int dt = 0; dt < 8; dt++)
        Op[(rbase + r) * C2_ + dt * 16 + l16] = (f16)Oa[mt][dt][rg];
      if (l16 == 0) ls[rbase + r] = lac[mt][rg];
    }
}

// ---------------------------------------------------------------------------
// conv2 + fused NS-split-combine + scale + residual. O view [128][4096]/batch;
// within a (j, pt)-tile the source row q = j*32 + (pt>>1) is constant per j,
// so normalization sum_s(Os)/sum_s(ls) folds into the staging pass.
// Grid (8, 64, 2) -> 4 WG/CU.
// ---------------------------------------------------------------------------
__global__ __launch_bounds__(256, 4)
void conv2_kernel(const f16* __restrict__ Op, const float* __restrict__ ls,
                  const f16* __restrict__ w2h,
                  const float* __restrict__ b2,
                  const float* __restrict__ scale,
                  const float* __restrict__ x,
                  float* __restrict__ out, int ns)
{
  __shared__ f16 Or[128 * 72];      // [j][p_local]
  __shared__ f16 Bsw[64 * 128];     // [p][j] XOR-16
  __shared__ float invL[128];

  const int t = threadIdx.x;
  const int w = t >> 6, lane = t & 63, quad = lane >> 4, l16 = lane & 15;
  const int b = blockIdx.x, pt = blockIdx.y, oh = blockIdx.z;
  const long base0 = (long)b * 524288;            // batch offset within a split

  if (t < 128) {
    int q = t * 32 + (pt >> 1);
    float l = 0.f;
    for (int si = 0; si < ns; si++)
      l += ls[(long)si * 32768 + (long)b * N_ + q];
    invL[t] = 1.0f / fmaxf(l, 1e-20f);
  }
  __syncthreads();

#pragma unroll
  for (int pass = 0; pass < 4; pass++) {
    int j = (t >> 3) + pass * 32;            // 0..127
    int c8 = (t & 7) * 8;                    // p_local
    float fa[8] = {0.f,0.f,0.f,0.f,0.f,0.f,0.f,0.f};
    for (int si = 0; si < ns; si++) {
      f16x8 a = *(const f16x8*)(Op + (long)si * 4194304 + base0 + (long)j * N_ + pt * 64 + c8);
#pragma unroll
      for (int jj = 0; jj < 8; jj++) fa[jj] += (float)a[jj];
    }
    float iv = invL[j];
    f16x8 r;
#pragma unroll
    for (int jj = 0; jj < 8; jj++)
      r[jj] = (f16)(fa[jj] * iv);
    *(f16x8*)(&Or[j * 72 + c8]) = r;
  }
  __syncthreads();
#pragma unroll
  for (int pass = 0; pass < 4; pass++) {
    int p = t & 63;
    int q = (t >> 6) + pass * 4;             // j-block 0..15
    f16x8 vv;
#pragma unroll
    for (int jj = 0; jj < 8; jj++) vv[jj] = Or[(q * 8 + jj) * 72 + p];
    *(f16x8*)(&Bsw[p * 128 + ((q ^ (p & 15))) * 8]) = vv;
  }
  __syncthreads();

  f32x4 acc[2][4];
#pragma unroll
  for (int i = 0; i < 2; i++)
#pragma unroll
    for (int j = 0; j < 4; j++) acc[i][j] = (f32x4){0.f, 0.f, 0.f, 0.f};

#pragma unroll
  for (int ks = 0; ks < 4; ks++) {
    f16x8 bfr[4];
#pragma unroll
    for (int nt = 0; nt < 4; nt++)
      bfr[nt] = *(const f16x8*)(&Bsw[(nt * 16 + l16) * 128 + (((ks * 4 + quad) ^ l16)) * 8]);
#pragma unroll
    for (int mt = 0; mt < 2; mt++) {
      int o = oh * 128 + w * 32 + mt * 16 + l16;
      f16x8 ah = *(const f16x8*)(w2h + o * C2_ + ks * 32 + quad * 8);
#pragma unroll
      for (int nt = 0; nt < 4; nt++)
        acc[mt][nt] = __builtin_amdgcn_mfma_f32_16x16x32_f16(ah, bfr[nt], acc[mt][nt], 0, 0, 0);
    }
  }
#pragma unroll
  for (int mt = 0; mt < 2; mt++)
#pragma unroll
    for (int rg = 0; rg < 4; rg++) {
      int o = oh * 128 + w * 32 + mt * 16 + quad * 4 + rg;
      float so = scale[o], bo = b2[o];
#pragma unroll
      for (int nt = 0; nt < 4; nt++) {
        int p = pt * 64 + nt * 16 + l16;
        long xo = ((long)b * C_ + o) * N_ + p;
        out[xo] = (acc[mt][nt][rg] + bo) * so + x[xo];
      }
    }
}

extern "C" void kernel_launch(void* const* d_in, const int* in_sizes, int n_in,
                              void* d_out, int out_size, void* d_ws, size_t ws_size,
                              hipStream_t stream) {
  const float* x     = (const float*)d_in[0];
  const float* W1    = (const float*)d_in[1];
  const float* b1    = (const float*)d_in[2];
  const float* W2    = (const float*)d_in[3];
  const float* b2    = (const float*)d_in[4];
  const float* scale = (const float*)d_in[5];
  float* outp = (float*)d_out;

  const size_t NE = (size_t)B_ * N_ * C2_;       // 4,194,304
  const int ns = 2;   // residency is VGPR-capped at 2 WG/CU; ns>2 adds only Op traffic (R5)

  f16* Y   = (f16*)d_ws;                         // 8 MiB
  f16* Yt  = Y + NE;                             // 8 MiB
  f16* Op  = Yt + NE;                            // ns x 8 MiB (unnormalized)
  float* ls = (float*)(Op + (size_t)ns * NE);    // ns x 32768 f32 row sums
  f16* w1h = (f16*)(ls + (size_t)ns * 32768);
  f16* w2h = w1h + 32768;

  prep_kernel <<<dim3(128),       dim3(256), 0, stream>>>(W1, W2, w1h, w2h);
  conv1_kernel<<<dim3(8, 128),    dim3(256), 0, stream>>>(x, w1h, b1, Y, Yt);
  attn_kernel <<<dim3(8, 32, ns), dim3(256), 0, stream>>>(Y, Yt, Op, ls);
  conv2_kernel<<<dim3(8, 64, 2),  dim3(256), 0, stream>>>(Op, ls, w2h, b2, scale, x, outp, ns);
}

// Round 7
// 210.756 us; speedup vs baseline: 2.1337x; 1.0058x over previous
//
#include <hip/hip_runtime.h>

#define B_  8
#define C_  256
#define C2_ 128
#define N_  4096
#define LOG2E 1.44269504088896f

typedef _Float16 f16;
typedef _Float16 f16x8 __attribute__((ext_vector_type(8)));
typedef float f32x4  __attribute__((ext_vector_type(4)));

static __device__ __forceinline__ unsigned pk2(float a, float b) {
  return __builtin_bit_cast(unsigned, __builtin_amdgcn_cvt_pkrtz(a, b));  // v_cvt_pkrtz_f16_f32
}

// quad-row swap: r0 = {a.q0, b.q0, a.q2, b.q2}, r1 = {a.q1, b.q1, a.q3, b.q3}
static __device__ __forceinline__ void plane16_swap(unsigned a, unsigned b,
                                                    unsigned& r0, unsigned& r1) {
#if __has_builtin(__builtin_amdgcn_permlane16_swap)
  auto r = __builtin_amdgcn_permlane16_swap(a, b, false, false);
  r0 = (unsigned)r[0]; r1 = (unsigned)r[1];
#else
  asm volatile("v_permlane16_swap_b32 %0, %1" : "+v"(a), "+v"(b));
  r0 = a; r1 = b;
#endif
}

// ---------------------------------------------------------------------------
// prep: cast W1/W2 to f16 once (32768 elements each)
// ---------------------------------------------------------------------------
__global__ __launch_bounds__(256)
void prep_kernel(const float* __restrict__ W1, const float* __restrict__ W2,
                 f16* __restrict__ w1h, f16* __restrict__ w2h)
{
  int i = blockIdx.x * 256 + threadIdx.x;   // grid 128 -> 32768
  w1h[i] = (f16)W1[i];
  w2h[i] = (f16)W2[i];
}

// ---------------------------------------------------------------------------
// conv1: Y[b,n,c2] = sum_c x[b,c,n]*W1[c2,c] + b1; dual layout Y + Yt.
// (unchanged from verified baseline)
// ---------------------------------------------------------------------------
__global__ __launch_bounds__(256, 3)
void conv1_kernel(const float* __restrict__ x,
                  const f16* __restrict__ w1h,
                  const float* __restrict__ b1,
                  f16* __restrict__ Y, f16* __restrict__ Yt)
{
  __shared__ __align__(16) char smem[49152];
  float* Xr = (float*)smem;            // [256 c][32 n] f32, float4-block XOR (32 KB)
  f16*   Ah = (f16*)(smem + 32768);    // [32 n][256 k] f16 XOR-8 (16 KB)
  f16*   T  = (f16*)smem;              // [128 c2][40 n] epilogue alias

  const int t = threadIdx.x;
  const int w = t >> 6, lane = t & 63, quad = lane >> 4, l16 = lane & 15;
  const int b = blockIdx.x, nt0 = blockIdx.y;

  // stage all 256c x 32n fp32 (8 outstanding float4 loads)
#pragma unroll
  for (int pass = 0; pass < 8; pass++) {
    int c  = (t >> 3) + pass * 32;            // 0..255
    int n4 = t & 7;
    float4 v = *(const float4*)(x + ((long)(b * C_ + c)) * N_ + nt0 * 32 + n4 * 4);
    *(float4*)(&Xr[c * 32 + (n4 ^ (c & 7)) * 4]) = v;
  }
  __syncthreads();
  // transpose+cvt into Ah [n][k] XOR-8
#pragma unroll
  for (int pass = 0; pass < 4; pass++) {
    int n  = t & 31;
    int kb = (t >> 5) + pass * 8;             // 0..31
    f16x8 vh;
#pragma unroll
    for (int jj = 0; jj < 8; jj++) {
      int cc = kb * 8 + jj;
      vh[jj] = (f16)Xr[cc * 32 + ((n >> 2) ^ (cc & 7)) * 4 + (n & 3)];
    }
    *(f16x8*)(&Ah[n * 256 + (kb ^ (n & 7)) * 8]) = vh;
  }
  __syncthreads();

  // B-frags from global (L2-hot, shared by all WGs)
  f16x8 bh[2][8];
#pragma unroll
  for (int nt = 0; nt < 2; nt++) {
    int c2 = w * 32 + nt * 16 + l16;
#pragma unroll
    for (int ks = 0; ks < 8; ks++)
      bh[nt][ks] = *(const f16x8*)(w1h + c2 * C_ + ks * 32 + quad * 8);
  }

  f32x4 acc[2][2];
#pragma unroll
  for (int i = 0; i < 2; i++)
#pragma unroll
    for (int j = 0; j < 2; j++) acc[i][j] = (f32x4){0.f, 0.f, 0.f, 0.f};

#pragma unroll
  for (int ks = 0; ks < 8; ks++)
#pragma unroll
    for (int mt = 0; mt < 2; mt++) {
      f16x8 ah = *(const f16x8*)(&Ah[(mt * 16 + l16) * 256 + (((ks * 4 + quad) ^ (l16 & 7))) * 8]);
#pragma unroll
      for (int nt = 0; nt < 2; nt++)
        acc[mt][nt] = __builtin_amdgcn_mfma_f32_16x16x32_f16(ah, bh[nt][ks], acc[mt][nt], 0, 0, 0);
    }
  __syncthreads();   // Xr dead -> T alias safe

  // epilogue -> T[c2][n]
#pragma unroll
  for (int nt = 0; nt < 2; nt++) {
    int c2 = w * 32 + nt * 16 + l16;
    float bv = b1[c2];
#pragma unroll
    for (int mt = 0; mt < 2; mt++)
#pragma unroll
      for (int rg = 0; rg < 4; rg++) {
        int n = mt * 16 + quad * 4 + rg;
        T[c2 * 40 + n] = (f16)(acc[mt][nt][rg] + bv);
      }
  }
  __syncthreads();
  // Yt[c2][n]: vec8 along n
#pragma unroll
  for (int pass = 0; pass < 2; pass++) {
    int r  = (t >> 2) + pass * 64;            // c2 0..127
    int c8 = (t & 3) * 8;                     // n
    f16x8 v = *(const f16x8*)(&T[r * 40 + c8]);
    *(f16x8*)(Yt + ((long)(b * C2_ + r)) * N_ + nt0 * 32 + c8) = v;
  }
  // Y[n][c2]: gather
#pragma unroll
  for (int pass = 0; pass < 2; pass++) {
    int row = t & 31;
    int cg  = (t >> 5) + pass * 8;            // c2-block 0..15
    f16x8 v;
#pragma unroll
    for (int jj = 0; jj < 8; jj++) v[jj] = T[(cg * 8 + jj) * 40 + row];
    *(f16x8*)(Y + ((long)(b * N_ + nt0 * 32 + row)) * C2_ + cg * 8) = v;
  }
}

// ---------------------------------------------------------------------------
// attn v7: R2/R5-verified structure (swapped QK^T, register P, conflict-free
// 16x16x32 PV, 2-barrier single-buffer loop — R6 proved barriers aren't the
// stall) with:
//  (a) pure-VALU P exchange: permlane32_swap + permlane16_swap (gfx950 quad-
//      row swap) replace 16 ds_swizzle + 16 cndmask. Derivation: target quad
//      q needs source quads {2(q&1), 2(q&1)+1} of S-reg nt=(q>>1)+2*ks2;
//      c0,c1 = pl32(a,b) -> {a.q01,b.q01},{a.q23,b.q23};
//      e0,e1 = pl16(c0,c1) -> {a.q0,a.q2,b.q0,b.q2} = (sq_lo,d) dword,
//                             {a.q1,a.q3,b.q1,b.q3} = (sq_hi,d) dword.
//  (b) T5 s_setprio(1) around MFMA clusters (2 async blocks/CU give the
//      scheduler phase diversity to arbitrate).
// launch_bounds(256,2): do NOT tighten (R4: forced 64 VGPR = 717 MB spill).
// Occupancy is VGPR-capped at 2 WG/CU (R4/R5 evidence) — expected ~19%.
// ---------------------------------------------------------------------------
__global__ __launch_bounds__(256, 2)
void attn_kernel(const f16* __restrict__ Y, const f16* __restrict__ Yt,
                 f16* __restrict__ Op, float* __restrict__ ls)
{
  __shared__ f16 Ks[64 * 128];   // [key][d]  16B-block pos = (d>>3) ^ (key&15)
  __shared__ f16 Vs[128 * 64];   // [d][k]    pos = (k>>3) ^ (d&7)
  __shared__ float nsqf[128];

  const int t = threadIdx.x;
  const int w = t >> 6, lane = t & 63, quad = lane >> 4, l16 = lane & 15;
  const int b = blockIdx.x, qt = blockIdx.y, s = blockIdx.z;
  const int ns = gridDim.z;
  const f16* Yb  = Y  + (long)b * N_ * C2_;
  const f16* Ytb = Yt + (long)b * C2_ * N_;
  const int g0 = (s * 64) / ns;        // first 64-key tile of this split
  const int g1 = ((s + 1) * 64) / ns;  // one past last

  // Q frags (A/B-frag layout identical for 16x16x32): row q=l16, d-chunk quad*8
  f16x8 qf[2][4];
#pragma unroll
  for (int mt = 0; mt < 2; mt++)
#pragma unroll
    for (int ks = 0; ks < 4; ks++)
      qf[mt][ks] = *(const f16x8*)(Yb + (long)(qt * 128 + w * 32 + mt * 16 + l16) * C2_ + ks * 32 + quad * 8);

  // per-row |y_q|^2 (exact same f16 values the MFMA sees)
  {
    int r = t >> 1, half = t & 1;
    float ss = 0.f;
#pragma unroll
    for (int j = 0; j < 8; j++) {
      f16x8 v = *(const f16x8*)(Yb + (long)(qt * 128 + r) * C2_ + half * 64 + j * 8);
#pragma unroll
      for (int e = 0; e < 8; e++) { float f = (float)v[e]; ss = fmaf(f, f, ss); }
    }
    ss += __shfl_xor(ss, 1);
    if (!half) nsqf[r] = ss;
  }

  // prologue: stage first tile of this split
  {
    const int kb0 = g0 * 64;
#pragma unroll
    for (int pass = 0; pass < 4; pass++) {
      int r = (t >> 4) + pass * 16;
      f16x8 kv = *(const f16x8*)(Yb + (long)(kb0 + r) * C2_ + (t & 15) * 8);
      *(f16x8*)(&Ks[r * 128 + (((t & 15)) ^ (r & 15)) * 8]) = kv;
    }
#pragma unroll
    for (int pass = 0; pass < 4; pass++) {
      int d = (t >> 3) + pass * 32;
      f16x8 vv = *(const f16x8*)(Ytb + (long)d * N_ + kb0 + (t & 7) * 8);
      *(f16x8*)(&Vs[d * 64 + (((t & 7)) ^ (d & 7)) * 8]) = vv;
    }
  }
  __syncthreads();

  // fixed per-row max (log2 units), per-lane by q=l16
  float nm[2];
  nm[0] = nsqf[w * 32 + l16] * LOG2E;
  nm[1] = nsqf[w * 32 + 16 + l16] * LOG2E;

  f16x8 ones8;
#pragma unroll
  for (int j = 0; j < 8; j++) ones8[j] = (f16)1.0f;

  f32x4 Oa[2][8];                 // C-layout: row q = quad*4+rg, col d = l16
#pragma unroll
  for (int i = 0; i < 2; i++)
#pragma unroll
    for (int j = 0; j < 8; j++) Oa[i][j] = (f32x4){0.f, 0.f, 0.f, 0.f};
  f32x4 lac[2] = {(f32x4){0.f,0.f,0.f,0.f}, (f32x4){0.f,0.f,0.f,0.f}};

#pragma unroll 1
  for (int g = g0; g < g1; g++) {
    // prefetch next tile into registers
    f16x8 stK[4], stV[4];
    if (g + 1 < g1) {
      int nb = (g + 1) * 64;
#pragma unroll
      for (int pass = 0; pass < 4; pass++)
        stK[pass] = *(const f16x8*)(Yb + (long)(nb + (t >> 4) + pass * 16) * C2_ + (t & 15) * 8);
#pragma unroll
      for (int pass = 0; pass < 4; pass++)
        stV[pass] = *(const f16x8*)(Ytb + (long)((t >> 3) + pass * 32) * N_ + nb + (t & 7) * 8);
    }

    // S^T = K Q^T : row = key(quad*4+rg within nt), col = q(l16)
    f32x4 S[4][2];
#pragma unroll
    for (int i = 0; i < 4; i++)
#pragma unroll
      for (int j = 0; j < 2; j++) S[i][j] = (f32x4){0.f, 0.f, 0.f, 0.f};
#pragma unroll
    for (int ks = 0; ks < 4; ks++) {
      f16x8 bfr[4];
#pragma unroll
      for (int nt = 0; nt < 4; nt++)
        bfr[nt] = *(const f16x8*)(&Ks[(nt * 16 + l16) * 128 + (((ks * 4 + quad) ^ l16)) * 8]);
      __builtin_amdgcn_s_setprio(1);
#pragma unroll
      for (int nt = 0; nt < 4; nt++)
#pragma unroll
        for (int mt = 0; mt < 2; mt++)
          S[nt][mt] = __builtin_amdgcn_mfma_f32_16x16x32_f16(bfr[nt], qf[mt][ks], S[nt][mt], 0, 0, 0);
      __builtin_amdgcn_s_setprio(0);
    }

    // fixed-max exp -> packed f16 pairs: Xp[mt][nt][d] = keys quad*4+{2d,2d+1}
    unsigned Xp[2][4][2];
#pragma unroll
    for (int mt = 0; mt < 2; mt++)
#pragma unroll
      for (int nt = 0; nt < 4; nt++) {
        float p0 = exp2f(fminf(fmaf(S[nt][mt][0], LOG2E, -nm[mt]), 11.0f));
        float p1 = exp2f(fminf(fmaf(S[nt][mt][1], LOG2E, -nm[mt]), 11.0f));
        float p2 = exp2f(fminf(fmaf(S[nt][mt][2], LOG2E, -nm[mt]), 11.0f));
        float p3 = exp2f(fminf(fmaf(S[nt][mt][3], LOG2E, -nm[mt]), 11.0f));
        Xp[mt][nt][0] = pk2(p0, p1);
        Xp[mt][nt][1] = pk2(p2, p3);
      }

    // register exchange -> PV A-frags pa[ks2][mt] (P[q=l16][k=quad*8..+7])
    // pure VALU: per (mt,ks2,d) one permlane32_swap + one permlane16_swap
    f16x8 pa[2][2];
#pragma unroll
    for (int mt = 0; mt < 2; mt++)
#pragma unroll
      for (int ks2 = 0; ks2 < 2; ks2++) {
        union { unsigned u[4]; f16x8 v; } P;
#pragma unroll
        for (int d = 0; d < 2; d++) {
          auto c = __builtin_amdgcn_permlane32_swap(Xp[mt][2 * ks2][d], Xp[mt][2 * ks2 + 1][d], false, false);
          unsigned e0, e1;
          plane16_swap((unsigned)c[0], (unsigned)c[1], e0, e1);
          P.u[d]     = e0;   // (sq_lo, d): k quad*8 + {2d, 2d+1}
          P.u[2 + d] = e1;   // (sq_hi, d): k quad*8 + {4+2d, 5+2d}
        }
        pa[ks2][mt] = P.v;
      }

    // O += P V ; l += P 1  (conflict-free 16x16x32 structure)
#pragma unroll
    for (int ks2 = 0; ks2 < 2; ks2++) {
      f16x8 vb[8];
#pragma unroll
      for (int dt = 0; dt < 8; dt++)
        vb[dt] = *(const f16x8*)(&Vs[(dt * 16 + l16) * 64 + (((ks2 * 4 + quad) ^ (l16 & 7))) * 8]);
      __builtin_amdgcn_s_setprio(1);
#pragma unroll
      for (int mt = 0; mt < 2; mt++) {
#pragma unroll
        for (int dt = 0; dt < 8; dt++)
          Oa[mt][dt] = __builtin_amdgcn_mfma_f32_16x16x32_f16(pa[ks2][mt], vb[dt], Oa[mt][dt], 0, 0, 0);
        lac[mt] = __builtin_amdgcn_mfma_f32_16x16x32_f16(pa[ks2][mt], ones8, lac[mt], 0, 0, 0);
      }
      __builtin_amdgcn_s_setprio(0);
    }

    __syncthreads();   // all Ks/Vs reads done
    if (g + 1 < g1) {
#pragma unroll
      for (int pass = 0; pass < 4; pass++) {
        int r = (t >> 4) + pass * 16;
        *(f16x8*)(&Ks[r * 128 + (((t & 15)) ^ (r & 15)) * 8]) = stK[pass];
      }
#pragma unroll
      for (int pass = 0; pass < 4; pass++) {
        int d = (t >> 3) + pass * 32;
        *(f16x8*)(&Vs[d * 64 + (((t & 7)) ^ (d & 7)) * 8]) = stV[pass];
      }
    }
    __syncthreads();
  }

  // epilogue: unnormalized O + row sums l (C-layout: row q, col d)
  const long rbase = ((long)s * B_ + b) * N_ + qt * 128;
#pragma unroll
  for (int mt = 0; mt < 2; mt++)
#pragma unroll
    for (int rg = 0; rg < 4; rg++) {
      int r = w * 32 + mt * 16 + quad * 4 + rg;
#pragma unroll
      for (int dt = 0; dt < 8; dt++)
        Op[(rbase + r) * C2_ + dt * 16 + l16] = (f16)Oa[mt][dt][rg];
      if (l16 == 0) ls[rbase + r] = lac[mt][rg];
    }
}

// ---------------------------------------------------------------------------
// conv2 + fused NS-split-combine + scale + residual. O view [128][4096]/batch;
// within a (j, pt)-tile the source row q = j*32 + (pt>>1) is constant per j,
// so normalization sum_s(Os)/sum_s(ls) folds into the staging pass.
// Grid (8, 64, 2) -> 4 WG/CU.
// ---------------------------------------------------------------------------
__global__ __launch_bounds__(256, 4)
void conv2_kernel(const f16* __restrict__ Op, const float* __restrict__ ls,
                  const f16* __restrict__ w2h,
                  const float* __restrict__ b2,
                  const float* __restrict__ scale,
                  const float* __restrict__ x,
                  float* __restrict__ out, int ns)
{
  __shared__ f16 Or[128 * 72];      // [j][p_local]
  __shared__ f16 Bsw[64 * 128];     // [p][j] XOR-16
  __shared__ float invL[128];

  const int t = threadIdx.x;
  const int w = t >> 6, lane = t & 63, quad = lane >> 4, l16 = lane & 15;
  const int b = blockIdx.x, pt = blockIdx.y, oh = blockIdx.z;
  const long base0 = (long)b * 524288;            // batch offset within a split

  if (t < 128) {
    int q = t * 32 + (pt >> 1);
    float l = 0.f;
    for (int si = 0; si < ns; si++)
      l += ls[(long)si * 32768 + (long)b * N_ + q];
    invL[t] = 1.0f / fmaxf(l, 1e-20f);
  }
  __syncthreads();

#pragma unroll
  for (int pass = 0; pass < 4; pass++) {
    int j = (t >> 3) + pass * 32;            // 0..127
    int c8 = (t & 7) * 8;                    // p_local
    float fa[8] = {0.f,0.f,0.f,0.f,0.f,0.f,0.f,0.f};
    for (int si = 0; si < ns; si++) {
      f16x8 a = *(const f16x8*)(Op + (long)si * 4194304 + base0 + (long)j * N_ + pt * 64 + c8);
#pragma unroll
      for (int jj = 0; jj < 8; jj++) fa[jj] += (float)a[jj];
    }
    float iv = invL[j];
    f16x8 r;
#pragma unroll
    for (int jj = 0; jj < 8; jj++)
      r[jj] = (f16)(fa[jj] * iv);
    *(f16x8*)(&Or[j * 72 + c8]) = r;
  }
  __syncthreads();
#pragma unroll
  for (int pass = 0; pass < 4; pass++) {
    int p = t & 63;
    int q = (t >> 6) + pass * 4;             // j-block 0..15
    f16x8 vv;
#pragma unroll
    for (int jj = 0; jj < 8; jj++) vv[jj] = Or[(q * 8 + jj) * 72 + p];
    *(f16x8*)(&Bsw[p * 128 + ((q ^ (p & 15))) * 8]) = vv;
  }
  __syncthreads();

  f32x4 acc[2][4];
#pragma unroll
  for (int i = 0; i < 2; i++)
#pragma unroll
    for (int j = 0; j < 4; j++) acc[i][j] = (f32x4){0.f, 0.f, 0.f, 0.f};

#pragma unroll
  for (int ks = 0; ks < 4; ks++) {
    f16x8 bfr[4];
#pragma unroll
    for (int nt = 0; nt < 4; nt++)
      bfr[nt] = *(const f16x8*)(&Bsw[(nt * 16 + l16) * 128 + (((ks * 4 + quad) ^ l16)) * 8]);
#pragma unroll
    for (int mt = 0; mt < 2; mt++) {
      int o = oh * 128 + w * 32 + mt * 16 + l16;
      f16x8 ah = *(const f16x8*)(w2h + o * C2_ + ks * 32 + quad * 8);
#pragma unroll
      for (int nt = 0; nt < 4; nt++)
        acc[mt][nt] = __builtin_amdgcn_mfma_f32_16x16x32_f16(ah, bfr[nt], acc[mt][nt], 0, 0, 0);
    }
  }
#pragma unroll
  for (int mt = 0; mt < 2; mt++)
#pragma unroll
    for (int rg = 0; rg < 4; rg++) {
      int o = oh * 128 + w * 32 + mt * 16 + quad * 4 + rg;
      float so = scale[o], bo = b2[o];
#pragma unroll
      for (int nt = 0; nt < 4; nt++) {
        int p = pt * 64 + nt * 16 + l16;
        long xo = ((long)b * C_ + o) * N_ + p;
        out[xo] = (acc[mt][nt][rg] + bo) * so + x[xo];
      }
    }
}

extern "C" void kernel_launch(void* const* d_in, const int* in_sizes, int n_in,
                              void* d_out, int out_size, void* d_ws, size_t ws_size,
                              hipStream_t stream) {
  const float* x     = (const float*)d_in[0];
  const float* W1    = (const float*)d_in[1];
  const float* b1    = (const float*)d_in[2];
  const float* W2    = (const float*)d_in[3];
  const float* b2    = (const float*)d_in[4];
  const float* scale = (const float*)d_in[5];
  float* outp = (float*)d_out;

  const size_t NE = (size_t)B_ * N_ * C2_;       // 4,194,304
  const int ns = 2;   // residency is VGPR-capped at 2 WG/CU; ns>2 only adds Op traffic (R5)

  f16* Y   = (f16*)d_ws;                         // 8 MiB
  f16* Yt  = Y + NE;                             // 8 MiB
  f16* Op  = Yt + NE;                            // ns x 8 MiB (unnormalized)
  float* ls = (float*)(Op + (size_t)ns * NE);    // ns x 32768 f32 row sums
  f16* w1h = (f16*)(ls + (size_t)ns * 32768);
  f16* w2h = w1h + 32768;

  prep_kernel <<<dim3(128),       dim3(256), 0, stream>>>(W1, W2, w1h, w2h);
  conv1_kernel<<<dim3(8, 128),    dim3(256), 0, stream>>>(x, w1h, b1, Y, Yt);
  attn_kernel <<<dim3(8, 32, ns), dim3(256), 0, stream>>>(Y, Yt, Op, ls);
  conv2_kernel<<<dim3(8, 64, 2),  dim3(256), 0, stream>>>(Op, ls, w2h, b2, scale, x, outp, ns);
}

// Round 8
// 208.735 us; speedup vs baseline: 2.1544x; 1.0097x over previous
//
#include <hip/hip_runtime.h>

#define B_  8
#define C_  256
#define C2_ 128
#define N_  4096
#define LOG2E 1.44269504088896f

typedef _Float16 f16;
typedef _Float16 f16x8 __attribute__((ext_vector_type(8)));
typedef float f32x4  __attribute__((ext_vector_type(4)));

static __device__ __forceinline__ unsigned pk2(float a, float b) {
  return __builtin_bit_cast(unsigned, __builtin_amdgcn_cvt_pkrtz(a, b));  // v_cvt_pkrtz_f16_f32
}

// quad-row swap: r0 = {a.q0, b.q0, a.q2, b.q2}, r1 = {a.q1, b.q1, a.q3, b.q3}
static __device__ __forceinline__ void plane16_swap(unsigned a, unsigned b,
                                                    unsigned& r0, unsigned& r1) {
#if __has_builtin(__builtin_amdgcn_permlane16_swap)
  auto r = __builtin_amdgcn_permlane16_swap(a, b, false, false);
  r0 = (unsigned)r[0]; r1 = (unsigned)r[1];
#else
  asm volatile("v_permlane16_swap_b32 %0, %1" : "+v"(a), "+v"(b));
  r0 = a; r1 = b;
#endif
}

// ---------------------------------------------------------------------------
// prep: cast W1/W2 to f16 once (32768 elements each)
// ---------------------------------------------------------------------------
__global__ __launch_bounds__(256)
void prep_kernel(const float* __restrict__ W1, const float* __restrict__ W2,
                 f16* __restrict__ w1h, f16* __restrict__ w2h)
{
  int i = blockIdx.x * 256 + threadIdx.x;   // grid 128 -> 32768
  w1h[i] = (f16)W1[i];
  w2h[i] = (f16)W2[i];
}

// ---------------------------------------------------------------------------
// conv1: Y[b,n,c2] = sum_c x[b,c,n]*W1[c2,c] + b1; dual layout Y + Yt.
// (unchanged from verified baseline)
// ---------------------------------------------------------------------------
__global__ __launch_bounds__(256, 3)
void conv1_kernel(const float* __restrict__ x,
                  const f16* __restrict__ w1h,
                  const float* __restrict__ b1,
                  f16* __restrict__ Y, f16* __restrict__ Yt)
{
  __shared__ __align__(16) char smem[49152];
  float* Xr = (float*)smem;            // [256 c][32 n] f32, float4-block XOR (32 KB)
  f16*   Ah = (f16*)(smem + 32768);    // [32 n][256 k] f16 XOR-8 (16 KB)
  f16*   T  = (f16*)smem;              // [128 c2][40 n] epilogue alias

  const int t = threadIdx.x;
  const int w = t >> 6, lane = t & 63, quad = lane >> 4, l16 = lane & 15;
  const int b = blockIdx.x, nt0 = blockIdx.y;

  // stage all 256c x 32n fp32 (8 outstanding float4 loads)
#pragma unroll
  for (int pass = 0; pass < 8; pass++) {
    int c  = (t >> 3) + pass * 32;            // 0..255
    int n4 = t & 7;
    float4 v = *(const float4*)(x + ((long)(b * C_ + c)) * N_ + nt0 * 32 + n4 * 4);
    *(float4*)(&Xr[c * 32 + (n4 ^ (c & 7)) * 4]) = v;
  }
  __syncthreads();
  // transpose+cvt into Ah [n][k] XOR-8
#pragma unroll
  for (int pass = 0; pass < 4; pass++) {
    int n  = t & 31;
    int kb = (t >> 5) + pass * 8;             // 0..31
    f16x8 vh;
#pragma unroll
    for (int jj = 0; jj < 8; jj++) {
      int cc = kb * 8 + jj;
      vh[jj] = (f16)Xr[cc * 32 + ((n >> 2) ^ (cc & 7)) * 4 + (n & 3)];
    }
    *(f16x8*)(&Ah[n * 256 + (kb ^ (n & 7)) * 8]) = vh;
  }
  __syncthreads();

  // B-frags from global (L2-hot, shared by all WGs)
  f16x8 bh[2][8];
#pragma unroll
  for (int nt = 0; nt < 2; nt++) {
    int c2 = w * 32 + nt * 16 + l16;
#pragma unroll
    for (int ks = 0; ks < 8; ks++)
      bh[nt][ks] = *(const f16x8*)(w1h + c2 * C_ + ks * 32 + quad * 8);
  }

  f32x4 acc[2][2];
#pragma unroll
  for (int i = 0; i < 2; i++)
#pragma unroll
    for (int j = 0; j < 2; j++) acc[i][j] = (f32x4){0.f, 0.f, 0.f, 0.f};

#pragma unroll
  for (int ks = 0; ks < 8; ks++)
#pragma unroll
    for (int mt = 0; mt < 2; mt++) {
      f16x8 ah = *(const f16x8*)(&Ah[(mt * 16 + l16) * 256 + (((ks * 4 + quad) ^ (l16 & 7))) * 8]);
#pragma unroll
      for (int nt = 0; nt < 2; nt++)
        acc[mt][nt] = __builtin_amdgcn_mfma_f32_16x16x32_f16(ah, bh[nt][ks], acc[mt][nt], 0, 0, 0);
    }
  __syncthreads();   // Xr dead -> T alias safe

  // epilogue -> T[c2][n]
#pragma unroll
  for (int nt = 0; nt < 2; nt++) {
    int c2 = w * 32 + nt * 16 + l16;
    float bv = b1[c2];
#pragma unroll
    for (int mt = 0; mt < 2; mt++)
#pragma unroll
      for (int rg = 0; rg < 4; rg++) {
        int n = mt * 16 + quad * 4 + rg;
        T[c2 * 40 + n] = (f16)(acc[mt][nt][rg] + bv);
      }
  }
  __syncthreads();
  // Yt[c2][n]: vec8 along n
#pragma unroll
  for (int pass = 0; pass < 2; pass++) {
    int r  = (t >> 2) + pass * 64;            // c2 0..127
    int c8 = (t & 3) * 8;                     // n
    f16x8 v = *(const f16x8*)(&T[r * 40 + c8]);
    *(f16x8*)(Yt + ((long)(b * C2_ + r)) * N_ + nt0 * 32 + c8) = v;
  }
  // Y[n][c2]: gather
#pragma unroll
  for (int pass = 0; pass < 2; pass++) {
    int row = t & 31;
    int cg  = (t >> 5) + pass * 8;            // c2-block 0..15
    f16x8 v;
#pragma unroll
    for (int jj = 0; jj < 8; jj++) v[jj] = T[(cg * 8 + jj) * 40 + row];
    *(f16x8*)(Y + ((long)(b * N_ + nt0 * 32 + row)) * C2_ + cg * 8) = v;
  }
}

// ---------------------------------------------------------------------------
// attn v8: R7 kernel (swapped QK^T, register P via permlane32+permlane16
// exchange, conflict-free 16x16x32 PV) with the tile body SOFTWARE-PIPELINED
// for intra-wave cross-pipe overlap:
//   QKT-A (S0,S1 complete) -> QKT-B issue -> exp/exch half0 (VALU hides under
//   QKT-B MFMAs) -> PV0 -> exp/exch half1 (hides under PV0) -> PV1.
// R7's order finished all four S[nt] together, so the whole exp->exchange->PV
// chain was serial per wave; with 2 waves/SIMD that serial chain was exposed.
// Pure reordering: per-(nt,mt) S accumulation is independent across nt, and
// the exchange consumes nt-pairs (0,1)/(2,3) = exactly the halves.
// launch_bounds(256,2): do NOT tighten (R4: forced 64 VGPR = 717 MB spill).
// ---------------------------------------------------------------------------
__global__ __launch_bounds__(256, 2)
void attn_kernel(const f16* __restrict__ Y, const f16* __restrict__ Yt,
                 f16* __restrict__ Op, float* __restrict__ ls)
{
  __shared__ f16 Ks[64 * 128];   // [key][d]  16B-block pos = (d>>3) ^ (key&15)
  __shared__ f16 Vs[128 * 64];   // [d][k]    pos = (k>>3) ^ (d&7)
  __shared__ float nsqf[128];

  const int t = threadIdx.x;
  const int w = t >> 6, lane = t & 63, quad = lane >> 4, l16 = lane & 15;
  const int b = blockIdx.x, qt = blockIdx.y, s = blockIdx.z;
  const int ns = gridDim.z;
  const f16* Yb  = Y  + (long)b * N_ * C2_;
  const f16* Ytb = Yt + (long)b * C2_ * N_;
  const int g0 = (s * 64) / ns;        // first 64-key tile of this split
  const int g1 = ((s + 1) * 64) / ns;  // one past last

  // Q frags (A/B-frag layout identical for 16x16x32): row q=l16, d-chunk quad*8
  f16x8 qf[2][4];
#pragma unroll
  for (int mt = 0; mt < 2; mt++)
#pragma unroll
    for (int ks = 0; ks < 4; ks++)
      qf[mt][ks] = *(const f16x8*)(Yb + (long)(qt * 128 + w * 32 + mt * 16 + l16) * C2_ + ks * 32 + quad * 8);

  // per-row |y_q|^2 (exact same f16 values the MFMA sees)
  {
    int r = t >> 1, half = t & 1;
    float ss = 0.f;
#pragma unroll
    for (int j = 0; j < 8; j++) {
      f16x8 v = *(const f16x8*)(Yb + (long)(qt * 128 + r) * C2_ + half * 64 + j * 8);
#pragma unroll
      for (int e = 0; e < 8; e++) { float f = (float)v[e]; ss = fmaf(f, f, ss); }
    }
    ss += __shfl_xor(ss, 1);
    if (!half) nsqf[r] = ss;
  }

  // prologue: stage first tile of this split
  {
    const int kb0 = g0 * 64;
#pragma unroll
    for (int pass = 0; pass < 4; pass++) {
      int r = (t >> 4) + pass * 16;
      f16x8 kv = *(const f16x8*)(Yb + (long)(kb0 + r) * C2_ + (t & 15) * 8);
      *(f16x8*)(&Ks[r * 128 + (((t & 15)) ^ (r & 15)) * 8]) = kv;
    }
#pragma unroll
    for (int pass = 0; pass < 4; pass++) {
      int d = (t >> 3) + pass * 32;
      f16x8 vv = *(const f16x8*)(Ytb + (long)d * N_ + kb0 + (t & 7) * 8);
      *(f16x8*)(&Vs[d * 64 + (((t & 7)) ^ (d & 7)) * 8]) = vv;
    }
  }
  __syncthreads();

  // fixed per-row max (log2 units), per-lane by q=l16
  float nm[2];
  nm[0] = nsqf[w * 32 + l16] * LOG2E;
  nm[1] = nsqf[w * 32 + 16 + l16] * LOG2E;

  f16x8 ones8;
#pragma unroll
  for (int j = 0; j < 8; j++) ones8[j] = (f16)1.0f;

  f32x4 Oa[2][8];                 // C-layout: row q = quad*4+rg, col d = l16
#pragma unroll
  for (int i = 0; i < 2; i++)
#pragma unroll
    for (int j = 0; j < 8; j++) Oa[i][j] = (f32x4){0.f, 0.f, 0.f, 0.f};
  f32x4 lac[2] = {(f32x4){0.f,0.f,0.f,0.f}, (f32x4){0.f,0.f,0.f,0.f}};

#pragma unroll 1
  for (int g = g0; g < g1; g++) {
    // prefetch next tile into registers
    f16x8 stK[4], stV[4];
    if (g + 1 < g1) {
      int nb = (g + 1) * 64;
#pragma unroll
      for (int pass = 0; pass < 4; pass++)
        stK[pass] = *(const f16x8*)(Yb + (long)(nb + (t >> 4) + pass * 16) * C2_ + (t & 15) * 8);
#pragma unroll
      for (int pass = 0; pass < 4; pass++)
        stV[pass] = *(const f16x8*)(Ytb + (long)((t >> 3) + pass * 32) * N_ + nb + (t & 7) * 8);
    }

    // ---- QKT half A: S[0],S[1] (nt=0,1) complete first ----
    f32x4 S[4][2];
#pragma unroll
    for (int i = 0; i < 4; i++)
#pragma unroll
      for (int j = 0; j < 2; j++) S[i][j] = (f32x4){0.f, 0.f, 0.f, 0.f};
#pragma unroll
    for (int ks = 0; ks < 4; ks++) {
      f16x8 b0 = *(const f16x8*)(&Ks[(0 * 16 + l16) * 128 + (((ks * 4 + quad) ^ l16)) * 8]);
      f16x8 b1 = *(const f16x8*)(&Ks[(1 * 16 + l16) * 128 + (((ks * 4 + quad) ^ l16)) * 8]);
      __builtin_amdgcn_s_setprio(1);
#pragma unroll
      for (int mt = 0; mt < 2; mt++) {
        S[0][mt] = __builtin_amdgcn_mfma_f32_16x16x32_f16(b0, qf[mt][ks], S[0][mt], 0, 0, 0);
        S[1][mt] = __builtin_amdgcn_mfma_f32_16x16x32_f16(b1, qf[mt][ks], S[1][mt], 0, 0, 0);
      }
      __builtin_amdgcn_s_setprio(0);
    }
    // ---- QKT half B: S[2],S[3] issue (exp half0 hides under these) ----
#pragma unroll
    for (int ks = 0; ks < 4; ks++) {
      f16x8 b2 = *(const f16x8*)(&Ks[(2 * 16 + l16) * 128 + (((ks * 4 + quad) ^ l16)) * 8]);
      f16x8 b3 = *(const f16x8*)(&Ks[(3 * 16 + l16) * 128 + (((ks * 4 + quad) ^ l16)) * 8]);
      __builtin_amdgcn_s_setprio(1);
#pragma unroll
      for (int mt = 0; mt < 2; mt++) {
        S[2][mt] = __builtin_amdgcn_mfma_f32_16x16x32_f16(b2, qf[mt][ks], S[2][mt], 0, 0, 0);
        S[3][mt] = __builtin_amdgcn_mfma_f32_16x16x32_f16(b3, qf[mt][ks], S[3][mt], 0, 0, 0);
      }
      __builtin_amdgcn_s_setprio(0);
    }

    // ---- exp + exchange half0 (S[0],S[1] -> pa0) : overlaps QKT-B ----
    f16x8 pa0[2];
#pragma unroll
    for (int mt = 0; mt < 2; mt++) {
      float n0 = nm[mt];
      unsigned xa0 = pk2(exp2f(fminf(fmaf(S[0][mt][0], LOG2E, -n0), 11.0f)),
                         exp2f(fminf(fmaf(S[0][mt][1], LOG2E, -n0), 11.0f)));
      unsigned xa1 = pk2(exp2f(fminf(fmaf(S[0][mt][2], LOG2E, -n0), 11.0f)),
                         exp2f(fminf(fmaf(S[0][mt][3], LOG2E, -n0), 11.0f)));
      unsigned xb0 = pk2(exp2f(fminf(fmaf(S[1][mt][0], LOG2E, -n0), 11.0f)),
                         exp2f(fminf(fmaf(S[1][mt][1], LOG2E, -n0), 11.0f)));
      unsigned xb1 = pk2(exp2f(fminf(fmaf(S[1][mt][2], LOG2E, -n0), 11.0f)),
                         exp2f(fminf(fmaf(S[1][mt][3], LOG2E, -n0), 11.0f)));
      union { unsigned u[4]; f16x8 v; } P;
      {
        auto c = __builtin_amdgcn_permlane32_swap(xa0, xb0, false, false);
        plane16_swap((unsigned)c[0], (unsigned)c[1], P.u[0], P.u[2]);
      }
      {
        auto c = __builtin_amdgcn_permlane32_swap(xa1, xb1, false, false);
        plane16_swap((unsigned)c[0], (unsigned)c[1], P.u[1], P.u[3]);
      }
      pa0[mt] = P.v;
    }

    // ---- PV0 (ks2=0) ----
    {
      f16x8 vb[8];
#pragma unroll
      for (int dt = 0; dt < 8; dt++)
        vb[dt] = *(const f16x8*)(&Vs[(dt * 16 + l16) * 64 + (((0 * 4 + quad) ^ (l16 & 7))) * 8]);
      __builtin_amdgcn_s_setprio(1);
#pragma unroll
      for (int mt = 0; mt < 2; mt++) {
#pragma unroll
        for (int dt = 0; dt < 8; dt++)
          Oa[mt][dt] = __builtin_amdgcn_mfma_f32_16x16x32_f16(pa0[mt], vb[dt], Oa[mt][dt], 0, 0, 0);
        lac[mt] = __builtin_amdgcn_mfma_f32_16x16x32_f16(pa0[mt], ones8, lac[mt], 0, 0, 0);
      }
      __builtin_amdgcn_s_setprio(0);
    }

    // ---- exp + exchange half1 (S[2],S[3] -> pa1) : overlaps PV0 ----
    f16x8 pa1[2];
#pragma unroll
    for (int mt = 0; mt < 2; mt++) {
      float n0 = nm[mt];
      unsigned xa0 = pk2(exp2f(fminf(fmaf(S[2][mt][0], LOG2E, -n0), 11.0f)),
                         exp2f(fminf(fmaf(S[2][mt][1], LOG2E, -n0), 11.0f)));
      unsigned xa1 = pk2(exp2f(fminf(fmaf(S[2][mt][2], LOG2E, -n0), 11.0f)),
                         exp2f(fminf(fmaf(S[2][mt][3], LOG2E, -n0), 11.0f)));
      unsigned xb0 = pk2(exp2f(fminf(fmaf(S[3][mt][0], LOG2E, -n0), 11.0f)),
                         exp2f(fminf(fmaf(S[3][mt][1], LOG2E, -n0), 11.0f)));
      unsigned xb1 = pk2(exp2f(fminf(fmaf(S[3][mt][2], LOG2E, -n0), 11.0f)),
                         exp2f(fminf(fmaf(S[3][mt][3], LOG2E, -n0), 11.0f)));
      union { unsigned u[4]; f16x8 v; } P;
      {
        auto c = __builtin_amdgcn_permlane32_swap(xa0, xb0, false, false);
        plane16_swap((unsigned)c[0], (unsigned)c[1], P.u[0], P.u[2]);
      }
      {
        auto c = __builtin_amdgcn_permlane32_swap(xa1, xb1, false, false);
        plane16_swap((unsigned)c[0], (unsigned)c[1], P.u[1], P.u[3]);
      }
      pa1[mt] = P.v;
    }

    // ---- PV1 (ks2=1) ----
    {
      f16x8 vb[8];
#pragma unroll
      for (int dt = 0; dt < 8; dt++)
        vb[dt] = *(const f16x8*)(&Vs[(dt * 16 + l16) * 64 + (((1 * 4 + quad) ^ (l16 & 7))) * 8]);
      __builtin_amdgcn_s_setprio(1);
#pragma unroll
      for (int mt = 0; mt < 2; mt++) {
#pragma unroll
        for (int dt = 0; dt < 8; dt++)
          Oa[mt][dt] = __builtin_amdgcn_mfma_f32_16x16x32_f16(pa1[mt], vb[dt], Oa[mt][dt], 0, 0, 0);
        lac[mt] = __builtin_amdgcn_mfma_f32_16x16x32_f16(pa1[mt], ones8, lac[mt], 0, 0, 0);
      }
      __builtin_amdgcn_s_setprio(0);
    }

    __syncthreads();   // all Ks/Vs reads done
    if (g + 1 < g1) {
#pragma unroll
      for (int pass = 0; pass < 4; pass++) {
        int r = (t >> 4) + pass * 16;
        *(f16x8*)(&Ks[r * 128 + (((t & 15)) ^ (r & 15)) * 8]) = stK[pass];
      }
#pragma unroll
      for (int pass = 0; pass < 4; pass++) {
        int d = (t >> 3) + pass * 32;
        *(f16x8*)(&Vs[d * 64 + (((t & 7)) ^ (d & 7)) * 8]) = stV[pass];
      }
    }
    __syncthreads();
  }

  // epilogue: unnormalized O + row sums l (C-layout: row q, col d)
  const long rbase = ((long)s * B_ + b) * N_ + qt * 128;
#pragma unroll
  for (int mt = 0; mt < 2; mt++)
#pragma unroll
    for (int rg = 0; rg < 4; rg++) {
      int r = w * 32 + mt * 16 + quad * 4 + rg;
#pragma unroll
      for (int dt = 0; dt < 8; dt++)
        Op[(rbase + r) * C2_ + dt * 16 + l16] = (f16)Oa[mt][dt][rg];
      if (l16 == 0) ls[rbase + r] = lac[mt][rg];
    }
}

// ---------------------------------------------------------------------------
// conv2 + fused NS-split-combine + scale + residual. O view [128][4096]/batch;
// within a (j, pt)-tile the source row q = j*32 + (pt>>1) is constant per j,
// so normalization sum_s(Os)/sum_s(ls) folds into the staging pass.
// Grid (8, 64, 2) -> 4 WG/CU.
// ---------------------------------------------------------------------------
__global__ __launch_bounds__(256, 4)
void conv2_kernel(const f16* __restrict__ Op, const float* __restrict__ ls,
                  const f16* __restrict__ w2h,
                  const float* __restrict__ b2,
                  const float* __restrict__ scale,
                  const float* __restrict__ x,
                  float* __restrict__ out, int ns)
{
  __shared__ f16 Or[128 * 72];      // [j][p_local]
  __shared__ f16 Bsw[64 * 128];     // [p][j] XOR-16
  __shared__ float invL[128];

  const int t = threadIdx.x;
  const int w = t >> 6, lane = t & 63, quad = lane >> 4, l16 = lane & 15;
  const int b = blockIdx.x, pt = blockIdx.y, oh = blockIdx.z;
  const long base0 = (long)b * 524288;            // batch offset within a split

  if (t < 128) {
    int q = t * 32 + (pt >> 1);
    float l = 0.f;
    for (int si = 0; si < ns; si++)
      l += ls[(long)si * 32768 + (long)b * N_ + q];
    invL[t] = 1.0f / fmaxf(l, 1e-20f);
  }
  __syncthreads();

#pragma unroll
  for (int pass = 0; pass < 4; pass++) {
    int j = (t >> 3) + pass * 32;            // 0..127
    int c8 = (t & 7) * 8;                    // p_local
    float fa[8] = {0.f,0.f,0.f,0.f,0.f,0.f,0.f,0.f};
    for (int si = 0; si < ns; si++) {
      f16x8 a = *(const f16x8*)(Op + (long)si * 4194304 + base0 + (long)j * N_ + pt * 64 + c8);
#pragma unroll
      for (int jj = 0; jj < 8; jj++) fa[jj] += (float)a[jj];
    }
    float iv = invL[j];
    f16x8 r;
#pragma unroll
    for (int jj = 0; jj < 8; jj++)
      r[jj] = (f16)(fa[jj] * iv);
    *(f16x8*)(&Or[j * 72 + c8]) = r;
  }
  __syncthreads();
#pragma unroll
  for (int pass = 0; pass < 4; pass++) {
    int p = t & 63;
    int q = (t >> 6) + pass * 4;             // j-block 0..15
    f16x8 vv;
#pragma unroll
    for (int jj = 0; jj < 8; jj++) vv[jj] = Or[(q * 8 + jj) * 72 + p];
    *(f16x8*)(&Bsw[p * 128 + ((q ^ (p & 15))) * 8]) = vv;
  }
  __syncthreads();

  f32x4 acc[2][4];
#pragma unroll
  for (int i = 0; i < 2; i++)
#pragma unroll
    for (int j = 0; j < 4; j++) acc[i][j] = (f32x4){0.f, 0.f, 0.f, 0.f};

#pragma unroll
  for (int ks = 0; ks < 4; ks++) {
    f16x8 bfr[4];
#pragma unroll
    for (int nt = 0; nt < 4; nt++)
      bfr[nt] = *(const f16x8*)(&Bsw[(nt * 16 + l16) * 128 + (((ks * 4 + quad) ^ l16)) * 8]);
#pragma unroll
    for (int mt = 0; mt < 2; mt++) {
      int o = oh * 128 + w * 32 + mt * 16 + l16;
      f16x8 ah = *(const f16x8*)(w2h + o * C2_ + ks * 32 + quad * 8);
#pragma unroll
      for (int nt = 0; nt < 4; nt++)
        acc[mt][nt] = __builtin_amdgcn_mfma_f32_16x16x32_f16(ah, bfr[nt], acc[mt][nt], 0, 0, 0);
    }
  }
#pragma unroll
  for (int mt = 0; mt < 2; mt++)
#pragma unroll
    for (int rg = 0; rg < 4; rg++) {
      int o = oh * 128 + w * 32 + mt * 16 + quad * 4 + rg;
      float so = scale[o], bo = b2[o];
#pragma unroll
      for (int nt = 0; nt < 4; nt++) {
        int p = pt * 64 + nt * 16 + l16;
        long xo = ((long)b * C_ + o) * N_ + p;
        out[xo] = (acc[mt][nt][rg] + bo) * so + x[xo];
      }
    }
}

extern "C" void kernel_launch(void* const* d_in, const int* in_sizes, int n_in,
                              void* d_out, int out_size, void* d_ws, size_t ws_size,
                              hipStream_t stream) {
  const float* x     = (const float*)d_in[0];
  const float* W1    = (const float*)d_in[1];
  const float* b1    = (const float*)d_in[2];
  const float* W2    = (const float*)d_in[3];
  const float* b2    = (const float*)d_in[4];
  const float* scale = (const float*)d_in[5];
  float* outp = (float*)d_out;

  const size_t NE = (size_t)B_ * N_ * C2_;       // 4,194,304
  const int ns = 2;   // residency is VGPR-capped at 2 WG/CU; ns>2 only adds Op traffic (R5)

  f16* Y   = (f16*)d_ws;                         // 8 MiB
  f16* Yt  = Y + NE;                             // 8 MiB
  f16* Op  = Yt + NE;                            // ns x 8 MiB (unnormalized)
  float* ls = (float*)(Op + (size_t)ns * NE);    // ns x 32768 f32 row sums
  f16* w1h = (f16*)(ls + (size_t)ns * 32768);
  f16* w2h = w1h + 32768;

  prep_kernel <<<dim3(128),       dim3(256), 0, stream>>>(W1, W2, w1h, w2h);
  conv1_kernel<<<dim3(8, 128),    dim3(256), 0, stream>>>(x, w1h, b1, Y, Yt);
  attn_kernel <<<dim3(8, 32, ns), dim3(256), 0, stream>>>(Y, Yt, Op, ls);
  conv2_kernel<<<dim3(8, 64, 2),  dim3(256), 0, stream>>>(Op, ls, w2h, b2, scale, x, outp, ns);
}